// Round 1
// baseline (2686.522 us; speedup 1.0000x reference)
//
#include <hip/hip_runtime.h>
#include <hip/hip_bf16.h>

#define BB 64
#define EE 1000
#define FF 4000
#define LQ_ 30
#define TT 100
#define EMB_ 300
#define G4 400
#define VERY_NEG_ (-100000000000.0f)
#define EPS_ 1e-10f

__device__ __forceinline__ float sigm(float x) { return 1.0f / (1.0f + expf(-x)); }

// ---------------------------------------------------------------- transpose
__global__ void transpose_kernel(const float* __restrict__ in, float* __restrict__ out,
                                 int rows, int cols) {
    int i = blockIdx.x * 256 + threadIdx.x;
    if (i < rows * cols) {
        int r = i / cols, c = i % cols;
        out[c * rows + r] = in[i];
    }
}

// ---------------------------------------------------------------- xw = word_emb[qtext] @ Wih.T + bih + bhh
__global__ __launch_bounds__(256)
void xw_kernel(const float* __restrict__ word_emb, const int* __restrict__ qtext,
               const float* __restrict__ WihT, const float* __restrict__ bih,
               const float* __restrict__ bhh, float* __restrict__ xw) {
    int bs = blockIdx.x;  // b*LQ + s
    __shared__ float x[EMB_];
    int wid = qtext[bs];
    for (int i = threadIdx.x; i < EMB_; i += 256) x[i] = word_emb[(long)wid * EMB_ + i];
    __syncthreads();
    for (int g = threadIdx.x; g < G4; g += 256) {
        float acc = bih[g] + bhh[g];
        #pragma unroll 4
        for (int k = 0; k < EMB_; ++k) acc += x[k] * WihT[k * G4 + g];
        xw[(long)bs * G4 + g] = acc;
    }
}

// ---------------------------------------------------------------- LSTM recurrence
__global__ __launch_bounds__(128)
void lstm_kernel(const float* __restrict__ xw, const float* __restrict__ WhhT,
                 float* __restrict__ qh_emb, float* __restrict__ qnode) {
    int b = blockIdx.x, tid = threadIdx.x;
    __shared__ float h[TT], c[TT], g[G4];
    if (tid < TT) { h[tid] = 0.f; c[tid] = 0.f; }
    __syncthreads();
    for (int s = 0; s < LQ_; ++s) {
        for (int gi = tid; gi < G4; gi += 128) {
            float acc = xw[((long)b * LQ_ + s) * G4 + gi];
            #pragma unroll 4
            for (int k = 0; k < TT; ++k) acc += h[k] * WhhT[k * G4 + gi];
            g[gi] = acc;
        }
        __syncthreads();
        if (tid < TT) {
            float ci = sigm(g[TT + tid]) * c[tid] + sigm(g[tid]) * tanhf(g[2 * TT + tid]);
            float hi = sigm(g[3 * TT + tid]) * tanhf(ci);
            c[tid] = ci; h[tid] = hi;
            qh_emb[((long)b * LQ_ + s) * TT + tid] = hi;
            if (s == LQ_ - 1) qnode[b * TT + tid] = hi;
        }
        __syncthreads();
    }
}

// ---------------------------------------------------------------- generic 100x100 linear
// Y[r,:] = act( X[gidx?gidx[r]:r, :] @ W.T + bias*bscale[r] + add[r,:] )
__global__ __launch_bounds__(256)
void lin100_kernel(const float* __restrict__ Xbase, const int* __restrict__ gidx,
                   const float* __restrict__ W, const float* __restrict__ bias,
                   const float* __restrict__ add, const float* __restrict__ bscale,
                   float* __restrict__ Y, int rows, int relu) {
    const int RPB = 64;
    __shared__ float Wl[TT * 101];
    __shared__ float Xl[RPB * 101];
    __shared__ float bl[TT];
    int tid = threadIdx.x;
    for (int i = tid; i < TT * TT; i += 256) Wl[(i / TT) * 101 + (i % TT)] = W[i];
    for (int i = tid; i < TT; i += 256) bl[i] = bias[i];
    long r0 = (long)blockIdx.x * RPB;
    int nr = (int)((rows - r0) < RPB ? (rows - r0) : RPB);
    for (int i = tid; i < RPB * TT; i += 256) {
        int r = i / TT, k = i % TT;
        float v = 0.f;
        if (r < nr) {
            long rr = r0 + r;
            long src = gidx ? ((long)gidx[rr] * TT + k) : (rr * TT + k);
            v = Xbase[src];
        }
        Xl[r * 101 + k] = v;
    }
    __syncthreads();
    // 2 rows x 4 cols per item; lanes consecutive in row-pair => W broadcast, X 2-way
    for (int it = tid; it < (RPB / 2) * 25; it += 256) {
        int rp = it & 31, gq = it >> 5;
        int r = rp * 2, t0 = gq * 4;
        float a00 = 0, a01 = 0, a02 = 0, a03 = 0, a10 = 0, a11 = 0, a12 = 0, a13 = 0;
        const float* x0 = &Xl[r * 101];
        const float* x1 = &Xl[(r + 1) * 101];
        #pragma unroll 4
        for (int k = 0; k < TT; ++k) {
            float xa = x0[k], xb = x1[k];
            float w0 = Wl[(t0 + 0) * 101 + k];
            float w1 = Wl[(t0 + 1) * 101 + k];
            float w2 = Wl[(t0 + 2) * 101 + k];
            float w3 = Wl[(t0 + 3) * 101 + k];
            a00 += xa * w0; a01 += xa * w1; a02 += xa * w2; a03 += xa * w3;
            a10 += xb * w0; a11 += xb * w1; a12 += xb * w2; a13 += xb * w3;
        }
        float acc[2][4] = {{a00, a01, a02, a03}, {a10, a11, a12, a13}};
        #pragma unroll
        for (int q = 0; q < 2; ++q) {
            if (r + q >= nr) break;
            long rr = r0 + r + q;
            float bsc = bscale ? bscale[rr] : 1.f;
            #pragma unroll
            for (int j = 0; j < 4; ++j) {
                float v = acc[q][j] + bl[t0 + j] * bsc;
                if (add) v += add[rr * TT + t0 + j];
                if (relu) v = fmaxf(v, 0.f);
                Y[rr * TT + t0 + j] = v;
            }
        }
    }
}

// ---------------------------------------------------------------- Wsc (fused sim/softmax/att)
__global__ __launch_bounds__(256)
void wsc_kernel(const float* __restrict__ qh_emb, const int* __restrict__ qtext,
                const float* __restrict__ fact_emb, float* __restrict__ Wsc) {
    int b = blockIdx.x >> 4;
    int chunk = blockIdx.x & 15;
    __shared__ float qh[LQ_ * TT];
    __shared__ float msk[LQ_];
    for (int i = threadIdx.x; i < LQ_ * TT; i += 256) qh[i] = qh_emb[(long)b * LQ_ * TT + i];
    for (int i = threadIdx.x; i < LQ_; i += 256)
        msk[i] = (qtext[b * LQ_ + i] != 0) ? 0.f : VERY_NEG_;
    __syncthreads();
    int f = chunk * 256 + threadIdx.x;
    if (f >= FF) return;
    const float* fr = &fact_emb[((long)b * FF + f) * TT];
    float sim[LQ_];
    #pragma unroll
    for (int l = 0; l < LQ_; ++l) sim[l] = 0.f;
    for (int k = 0; k < TT; ++k) {
        float x = fr[k];
        #pragma unroll
        for (int l = 0; l < LQ_; ++l) sim[l] += x * qh[l * TT + k];
    }
    float mx = -INFINITY;
    #pragma unroll
    for (int l = 0; l < LQ_; ++l) {
        sim[l] *= 0.1f;  // /sqrt(100)
        mx = fmaxf(mx, sim[l] + msk[l]);
    }
    float ssum = 0.f, wsum = 0.f;
    #pragma unroll
    for (int l = 0; l < LQ_; ++l) {
        float p = expf(sim[l] + msk[l] - mx);
        ssum += p;
        wsum += p * sim[l];
    }
    Wsc[(long)b * FF + f] = wsum / ssum;
}

// ---------------------------------------------------------------- row max over facts
__global__ __launch_bounds__(256)
void rowmax_kernel(const float* __restrict__ Wsc, float* __restrict__ bmax) {
    int b = blockIdx.x, tid = threadIdx.x;
    __shared__ float red[256];
    float m = -INFINITY;
    for (int f = tid; f < FF; f += 256) m = fmaxf(m, Wsc[(long)b * FF + f]);
    red[tid] = m;
    __syncthreads();
    for (int s = 128; s; s >>= 1) {
        if (tid < s) red[tid] = fmaxf(red[tid], red[tid + s]);
        __syncthreads();
    }
    if (tid == 0) bmax[b] = red[0];
}

// ---------------------------------------------------------------- W_tilde + scatter e2f_softmax + tail counts
__global__ __launch_bounds__(256)
void wtilde_kernel(const float* __restrict__ Wsc, const float* __restrict__ bmax,
                   const int* __restrict__ head, const int* __restrict__ tail,
                   float* __restrict__ W_tilde, float* __restrict__ e2f_sm,
                   float* __restrict__ cnt) {
    int idx = blockIdx.x * 256 + threadIdx.x;
    if (idx >= BB * FF) return;
    int b = idx / FF;
    float wt = expf(Wsc[idx] - bmax[b]);
    W_tilde[idx] = wt;
    atomicAdd(&e2f_sm[(long)b * EE + head[idx]], wt);
    atomicAdd(&cnt[(long)b * EE + tail[idx]], 1.f);
}

// ---------------------------------------------------------------- per-layer tiny: q2e_vec + cvecs
__global__ __launch_bounds__(128)
void qvec_kernel(const float* __restrict__ qnode,
                 const float* __restrict__ q2eW, const float* __restrict__ q2eb,
                 const float* __restrict__ e2eW, const float* __restrict__ e2eb,
                 const float* __restrict__ e2qW, const float* __restrict__ e2qb,
                 float* __restrict__ q2e_vec, float* __restrict__ cvec_e2e,
                 float* __restrict__ cvec_e2q) {
    int b = blockIdx.x, t = threadIdx.x;
    __shared__ float qn[TT], qv[TT];
    if (t < TT) qn[t] = qnode[b * TT + t];
    __syncthreads();
    if (t < TT) {
        float acc = q2eb[t];
        for (int k = 0; k < TT; ++k) acc += qn[k] * q2eW[t * TT + k];
        qv[t] = acc;
        q2e_vec[b * TT + t] = acc;
    }
    __syncthreads();
    if (t < TT) {
        float a1 = e2eb[t], a2 = e2qb[t];
        for (int k = 0; k < TT; ++k) {
            a1 += qv[k] * e2eW[(long)t * 300 + TT + k];
            a2 += qv[k] * e2qW[(long)t * 300 + TT + k];
        }
        cvec_e2e[b * TT + t] = a1;
        cvec_e2q[b * TT + t] = a2;
    }
}

// ---------------------------------------------------------------- e2f: kbs(fact) + kbh[head], relu, *norm, scatter by tail
__global__ __launch_bounds__(256)
void e2f_kernel(const float* __restrict__ fact_emb, const float* __restrict__ kbs_W,
                const float* __restrict__ kbs_b, const float* __restrict__ kbh,
                const float* __restrict__ W_tilde, const float* __restrict__ pr,
                const float* __restrict__ e2f_sm, const int* __restrict__ head,
                const int* __restrict__ tail, float* __restrict__ eacc,
                float* __restrict__ pr_acc) {
    const int FPB = 32;
    __shared__ float Wl[TT * 101];
    __shared__ float Xl[FPB * 101];
    __shared__ float Sl[FPB * 101];
    __shared__ float bl[TT];
    __shared__ float norml[FPB];
    __shared__ int headl[FPB], taill[FPB];
    int tid = threadIdx.x;
    long f0 = (long)blockIdx.x * FPB;  // 125 blocks per batch: never straddles b
    int b = (int)(f0 / FF);
    for (int i = tid; i < TT * TT; i += 256) Wl[(i / TT) * 101 + (i % TT)] = kbs_W[i];
    for (int i = tid; i < TT; i += 256) bl[i] = kbs_b[i];
    for (int i = tid; i < FPB * TT; i += 256) {
        int r = i / TT, k = i % TT;
        Xl[r * 101 + k] = fact_emb[(f0 + r) * TT + k];
    }
    if (tid < FPB) {
        long fg = f0 + tid;
        int h = head[fg], tl = tail[fg];
        headl[tid] = h; taill[tid] = tl;
        float sm = fmaxf(e2f_sm[(long)b * EE + h], EPS_);
        norml[tid] = W_tilde[fg] * pr[(long)b * EE + h] / sm;
    }
    __syncthreads();
    for (int it = tid; it < 16 * 25; it += 256) {
        int rp = it & 15, gq = it >> 4;
        int r = rp * 2, t0 = gq * 4;
        float a00 = 0, a01 = 0, a02 = 0, a03 = 0, a10 = 0, a11 = 0, a12 = 0, a13 = 0;
        const float* x0 = &Xl[r * 101];
        const float* x1 = &Xl[(r + 1) * 101];
        #pragma unroll 4
        for (int k = 0; k < TT; ++k) {
            float xa = x0[k], xb = x1[k];
            float w0 = Wl[(t0 + 0) * 101 + k];
            float w1 = Wl[(t0 + 1) * 101 + k];
            float w2 = Wl[(t0 + 2) * 101 + k];
            float w3 = Wl[(t0 + 3) * 101 + k];
            a00 += xa * w0; a01 += xa * w1; a02 += xa * w2; a03 += xa * w3;
            a10 += xb * w0; a11 += xb * w1; a12 += xb * w2; a13 += xb * w3;
        }
        Sl[r * 101 + t0 + 0] = a00 + bl[t0 + 0];
        Sl[r * 101 + t0 + 1] = a01 + bl[t0 + 1];
        Sl[r * 101 + t0 + 2] = a02 + bl[t0 + 2];
        Sl[r * 101 + t0 + 3] = a03 + bl[t0 + 3];
        Sl[(r + 1) * 101 + t0 + 0] = a10 + bl[t0 + 0];
        Sl[(r + 1) * 101 + t0 + 1] = a11 + bl[t0 + 1];
        Sl[(r + 1) * 101 + t0 + 2] = a12 + bl[t0 + 2];
        Sl[(r + 1) * 101 + t0 + 3] = a13 + bl[t0 + 3];
    }
    __syncthreads();
    for (int i = tid; i < FPB * TT; i += 256) {
        int f = i / TT, t = i % TT;
        float v = Sl[f * 101 + t] + kbh[((long)b * EE + headl[f]) * TT + t];
        v = fmaxf(v, 0.f) * norml[f];
        atomicAdd(&eacc[((long)b * EE + taill[f]) * TT + t], v);
    }
    if (tid < FPB) atomicAdd(&pr_acc[(long)b * EE + taill[tid]], norml[tid]);
}

// ---------------------------------------------------------------- pagerank update
__global__ void pr_update_kernel(const float* __restrict__ pr_acc, float* __restrict__ pr,
                                 float* __restrict__ out2) {
    int i = blockIdx.x * 256 + threadIdx.x;
    if (i < BB * EE) {
        float v = 0.8f * pr_acc[i] + 0.2f * pr[i];
        pr[i] = v;
        if (out2) out2[i] = v;
    }
}

// ---------------------------------------------------------------- weighted reductions s1,s3,prsum
__global__ __launch_bounds__(128)
void reduce_kernel(const float* __restrict__ pr, const float* __restrict__ ent,
                   const float* __restrict__ f2e, float* __restrict__ s1,
                   float* __restrict__ s3, float* __restrict__ prsum) {
    int b = blockIdx.x, tid = threadIdx.x;
    __shared__ float prl[EE];
    __shared__ float red[128];
    for (int e = tid; e < EE; e += 128) prl[e] = pr[(long)b * EE + e];
    __syncthreads();
    float ps = 0.f;
    for (int e = tid; e < EE; e += 128) ps += prl[e];
    red[tid] = ps;
    __syncthreads();
    for (int s = 64; s; s >>= 1) {
        if (tid < s) red[tid] += red[tid + s];
        __syncthreads();
    }
    if (tid == 0) prsum[b] = red[0];
    if (tid < TT) {
        float a1 = 0.f, a3 = 0.f;
        const float* eb = ent + (long)b * EE * TT;
        const float* fb = f2e + (long)b * EE * TT;
        for (int e = 0; e < EE; ++e) {
            float p = prl[e];
            a1 += p * eb[(long)e * TT + tid];
            a3 += p * fb[(long)e * TT + tid];
        }
        s1[b * TT + tid] = a1;
        s3[b * TT + tid] = a3;
    }
}

// ---------------------------------------------------------------- qnode update
__global__ __launch_bounds__(128)
void qnode_kernel(const float* __restrict__ s1, const float* __restrict__ s3,
                  const float* __restrict__ prsum, const float* __restrict__ cvec_e2q,
                  const float* __restrict__ e2qW, float* __restrict__ qnode,
                  float* __restrict__ out2) {
    int b = blockIdx.x, t = threadIdx.x;
    __shared__ float s1l[TT], s3l[TT];
    if (t < TT) { s1l[t] = s1[b * TT + t]; s3l[t] = s3[b * TT + t]; }
    __syncthreads();
    if (t < TT) {
        float acc = prsum[b] * cvec_e2q[b * TT + t];
        const float* wr = e2qW + (long)t * 300;
        for (int k = 0; k < TT; ++k) acc += s1l[k] * wr[k] + s3l[k] * wr[200 + k];
        qnode[b * TT + t] = acc;
        if (out2) out2[b * TT + t] = acc;
    }
}

// ---------------------------------------------------------------- e2e: relu(ent@W1.T + f2e@W3.T + cvec)
__global__ __launch_bounds__(256)
void e2e_kernel(const float* __restrict__ ent, const float* __restrict__ f2e,
                const float* __restrict__ W, const float* __restrict__ cvec,
                float* __restrict__ out) {
    const int RPB = 32;
    __shared__ float W1[TT * 101], W3[TT * 101];
    __shared__ float X1[RPB * 101], X3[RPB * 101];
    int tid = threadIdx.x;
    for (int i = tid; i < TT * TT; i += 256) {
        int t = i / TT, k = i % TT;
        W1[t * 101 + k] = W[(long)t * 300 + k];
        W3[t * 101 + k] = W[(long)t * 300 + 200 + k];
    }
    long r0 = (long)blockIdx.x * RPB;
    for (int i = tid; i < RPB * TT; i += 256) {
        int r = i / TT, k = i % TT;
        X1[r * 101 + k] = ent[(r0 + r) * TT + k];
        X3[r * 101 + k] = f2e[(r0 + r) * TT + k];
    }
    __syncthreads();
    for (int it = tid; it < 16 * 25; it += 256) {
        int rp = it & 15, gq = it >> 4;
        int r = rp * 2, t0 = gq * 4;
        float a00 = 0, a01 = 0, a02 = 0, a03 = 0, a10 = 0, a11 = 0, a12 = 0, a13 = 0;
        const float* x0 = &X1[r * 101];
        const float* x1 = &X1[(r + 1) * 101];
        #pragma unroll 4
        for (int k = 0; k < TT; ++k) {
            float xa = x0[k], xb = x1[k];
            float w0 = W1[(t0 + 0) * 101 + k];
            float w1 = W1[(t0 + 1) * 101 + k];
            float w2 = W1[(t0 + 2) * 101 + k];
            float w3 = W1[(t0 + 3) * 101 + k];
            a00 += xa * w0; a01 += xa * w1; a02 += xa * w2; a03 += xa * w3;
            a10 += xb * w0; a11 += xb * w1; a12 += xb * w2; a13 += xb * w3;
        }
        const float* y0 = &X3[r * 101];
        const float* y1 = &X3[(r + 1) * 101];
        #pragma unroll 4
        for (int k = 0; k < TT; ++k) {
            float xa = y0[k], xb = y1[k];
            float w0 = W3[(t0 + 0) * 101 + k];
            float w1 = W3[(t0 + 1) * 101 + k];
            float w2 = W3[(t0 + 2) * 101 + k];
            float w3 = W3[(t0 + 3) * 101 + k];
            a00 += xa * w0; a01 += xa * w1; a02 += xa * w2; a03 += xa * w3;
            a10 += xb * w0; a11 += xb * w1; a12 += xb * w2; a13 += xb * w3;
        }
        float acc[2][4] = {{a00, a01, a02, a03}, {a10, a11, a12, a13}};
        #pragma unroll
        for (int q = 0; q < 2; ++q) {
            long rr = r0 + r + q;
            int bq = (int)(rr / EE);
            #pragma unroll
            for (int j = 0; j < 4; ++j) {
                float v = acc[q][j] + cvec[bq * TT + t0 + j];
                out[rr * TT + t0 + j] = fmaxf(v, 0.f);
            }
        }
    }
}

// ================================================================ host
extern "C" void kernel_launch(void* const* d_in, const int* in_sizes, int n_in,
                              void* d_out, int out_size, void* d_ws, size_t ws_size,
                              hipStream_t stream) {
    const float* word_emb   = (const float*)d_in[0];
    const float* entity_emb = (const float*)d_in[1];
    const float* ent_W      = (const float*)d_in[2];
    const float* ent_b      = (const float*)d_in[3];
    const float* lstm_Wih   = (const float*)d_in[4];
    const float* lstm_Whh   = (const float*)d_in[5];
    const float* lstm_bih   = (const float*)d_in[6];
    const float* lstm_bhh   = (const float*)d_in[7];
    const float* q2e_W      = (const float*)d_in[8];
    const float* q2e_b      = (const float*)d_in[9];
    const float* e2q_W      = (const float*)d_in[10];
    const float* e2q_b      = (const float*)d_in[11];
    const float* e2e_W      = (const float*)d_in[12];
    const float* e2e_b      = (const float*)d_in[13];
    const float* kbh_W      = (const float*)d_in[14];
    const float* kbh_b      = (const float*)d_in[15];
    const float* kbt_W      = (const float*)d_in[16];
    const float* kbt_b      = (const float*)d_in[17];
    const float* kbs_W      = (const float*)d_in[18];
    const float* kbs_b      = (const float*)d_in[19];
    const float* q2e_adj    = (const float*)d_in[20];
    const int* query_text   = (const int*)d_in[21];
    const int* local_entity = (const int*)d_in[22];
    const int* kb_fact_rel  = (const int*)d_in[23];
    const int* head_idx     = (const int*)d_in[24];
    const int* tail_idx     = (const int*)d_in[25];
    float* out = (float*)d_out;

    float* w = (float*)d_ws;
    size_t off = 0;
    auto alloc = [&](size_t n) {
        float* p = w + off;
        off += (n + 255) & ~(size_t)255;
        return p;
    };
    float* fact_emb = alloc((size_t)BB * FF * TT);   // 25.6M
    float* entA     = alloc((size_t)BB * EE * TT);   // 6.4M
    float* entB     = alloc((size_t)BB * EE * TT);
    float* kbh      = alloc((size_t)BB * EE * TT);   // aliased as f2e after e2f
    float* kbs_e    = alloc((size_t)BB * EE * TT);
    float* eacc     = alloc((size_t)BB * EE * TT);
    float* xw       = alloc((size_t)BB * LQ_ * G4);
    float* qh_emb   = alloc((size_t)BB * LQ_ * TT);
    float* WihT     = alloc((size_t)G4 * EMB_);
    float* WhhT     = alloc((size_t)G4 * TT);
    float* Wsc      = alloc((size_t)BB * FF);
    float* W_tilde  = alloc((size_t)BB * FF);
    float* bmaxb    = alloc(BB);
    float* e2f_sm   = alloc((size_t)BB * EE);
    float* cnt      = alloc((size_t)BB * EE);
    float* pr       = alloc((size_t)BB * EE);
    float* pr_acc   = alloc((size_t)BB * EE);
    float* qnode    = alloc((size_t)BB * TT);
    float* q2e_vec  = alloc((size_t)BB * TT);
    float* cvec_e2e = alloc((size_t)BB * TT);
    float* cvec_e2q = alloc((size_t)BB * TT);
    float* s1       = alloc((size_t)BB * TT);
    float* s3       = alloc((size_t)BB * TT);
    float* prsum    = alloc(BB);
    float* f2e = kbh;  // alias: kbh dead after e2f_kernel

    // ---- LSTM path
    transpose_kernel<<<(G4 * EMB_ + 255) / 256, 256, 0, stream>>>(lstm_Wih, WihT, G4, EMB_);
    transpose_kernel<<<(G4 * TT + 255) / 256, 256, 0, stream>>>(lstm_Whh, WhhT, G4, TT);
    xw_kernel<<<BB * LQ_, 256, 0, stream>>>(word_emb, query_text, WihT, lstm_bih, lstm_bhh, xw);
    lstm_kernel<<<BB, 128, 0, stream>>>(xw, WhhT, qh_emb, qnode);

    // ---- embeddings
    lin100_kernel<<<(BB * FF) / 64, 256, 0, stream>>>(entity_emb, kb_fact_rel, ent_W, ent_b,
                                                      nullptr, nullptr, fact_emb, BB * FF, 0);
    lin100_kernel<<<(BB * EE) / 64, 256, 0, stream>>>(entity_emb, local_entity, ent_W, ent_b,
                                                      nullptr, nullptr, entA, BB * EE, 0);

    // ---- attention scores -> W_tilde, e2f_softmax, counts
    wsc_kernel<<<BB * 16, 256, 0, stream>>>(qh_emb, query_text, fact_emb, Wsc);
    rowmax_kernel<<<BB, 256, 0, stream>>>(Wsc, bmaxb);
    hipMemsetAsync(e2f_sm, 0, (size_t)BB * EE * 4, stream);
    hipMemsetAsync(cnt, 0, (size_t)BB * EE * 4, stream);
    wtilde_kernel<<<(BB * FF + 255) / 256, 256, 0, stream>>>(Wsc, bmaxb, head_idx, tail_idx,
                                                             W_tilde, e2f_sm, cnt);
    hipMemcpyAsync(pr, q2e_adj, (size_t)BB * EE * 4, hipMemcpyDeviceToDevice, stream);

    // ---- GNN layers
    for (int i = 0; i < 2; ++i) {
        const float* ent_in = i ? entB : entA;
        float* ent_out = i ? out : entB;
        qvec_kernel<<<BB, 128, 0, stream>>>(qnode, q2e_W + i * TT * TT, q2e_b + i * TT,
                                            e2e_W + i * TT * 300, e2e_b + i * TT,
                                            e2q_W + i * TT * 300, e2q_b + i * TT,
                                            q2e_vec, cvec_e2e, cvec_e2q);
        lin100_kernel<<<(BB * EE) / 64, 256, 0, stream>>>(ent_in, nullptr, kbh_W + i * TT * TT,
                                                          kbh_b + i * TT, nullptr, nullptr,
                                                          kbh, BB * EE, 0);
        lin100_kernel<<<(BB * EE) / 64, 256, 0, stream>>>(ent_in, nullptr, kbs_W + i * TT * TT,
                                                          kbs_b + i * TT, nullptr, nullptr,
                                                          kbs_e, BB * EE, 0);
        hipMemsetAsync(eacc, 0, (size_t)BB * EE * TT * 4, stream);
        hipMemsetAsync(pr_acc, 0, (size_t)BB * EE * 4, stream);
        e2f_kernel<<<(BB * FF) / 32, 256, 0, stream>>>(fact_emb, kbs_W + i * TT * TT,
                                                       kbs_b + i * TT, kbh, W_tilde, pr, e2f_sm,
                                                       head_idx, tail_idx, eacc, pr_acc);
        // f2e = relu(kbs_e + eacc@kbt.T + kbt_b*cnt)   (f2e aliases kbh)
        lin100_kernel<<<(BB * EE) / 64, 256, 0, stream>>>(eacc, nullptr, kbt_W + i * TT * TT,
                                                          kbt_b + i * TT, kbs_e, cnt,
                                                          f2e, BB * EE, 1);
        pr_update_kernel<<<(BB * EE + 255) / 256, 256, 0, stream>>>(
            pr_acc, pr, (i == 1) ? out + 6406400 : nullptr);
        reduce_kernel<<<BB, 128, 0, stream>>>(pr, ent_in, f2e, s1, s3, prsum);
        qnode_kernel<<<BB, 128, 0, stream>>>(s1, s3, prsum, cvec_e2q, e2q_W + i * TT * 300,
                                             qnode, (i == 1) ? out + 6400000 : nullptr);
        e2e_kernel<<<(BB * EE) / 32, 256, 0, stream>>>(ent_in, f2e, e2e_W + i * TT * 300,
                                                       cvec_e2e, ent_out);
    }
}

// Round 2
// 1510.817 us; speedup vs baseline: 1.7782x; 1.7782x over previous
//
#include <hip/hip_runtime.h>
#include <hip/hip_bf16.h>

#define BB 64
#define EE 1000
#define FF 4000
#define LQ_ 30
#define TT 100
#define EMB_ 300
#define G4 400
#define EV_ 50007
#define VERY_NEG_ (-100000000000.0f)
#define EPS_ 1e-10f

__device__ __forceinline__ float sigm(float x) { return 1.0f / (1.0f + expf(-x)); }

// ---------------------------------------------------------------- transpose
__global__ void transpose_kernel(const float* __restrict__ in, float* __restrict__ out,
                                 int rows, int cols) {
    int i = blockIdx.x * 256 + threadIdx.x;
    if (i < rows * cols) {
        int r = i / cols, c = i % cols;
        out[c * rows + r] = in[i];
    }
}

// ---------------------------------------------------------------- xw = word_emb[qtext] @ Wih.T + bih + bhh
__global__ __launch_bounds__(256)
void xw_kernel(const float* __restrict__ word_emb, const int* __restrict__ qtext,
               const float* __restrict__ WihT, const float* __restrict__ bih,
               const float* __restrict__ bhh, float* __restrict__ xw) {
    int bs = blockIdx.x;  // b*LQ + s
    __shared__ float x[EMB_];
    int wid = qtext[bs];
    for (int i = threadIdx.x; i < EMB_; i += 256) x[i] = word_emb[(long)wid * EMB_ + i];
    __syncthreads();
    for (int g = threadIdx.x; g < G4; g += 256) {
        float acc = bih[g] + bhh[g];
        #pragma unroll 4
        for (int k = 0; k < EMB_; ++k) acc += x[k] * WihT[k * G4 + g];
        xw[(long)bs * G4 + g] = acc;
    }
}

// ---------------------------------------------------------------- LSTM: weights in registers
__global__ __launch_bounds__(512)
void lstm_kernel(const float* __restrict__ xw, const float* __restrict__ Whh,
                 float* __restrict__ qh_emb, float* __restrict__ qnode) {
    int b = blockIdx.x, tid = threadIdx.x;
    __shared__ __align__(16) float hs[TT];
    __shared__ float cs[TT];
    __shared__ float gs[G4];
    float4 w[25];
    if (tid < G4) {
        const float4* wr = (const float4*)(Whh + (long)tid * TT);
        #pragma unroll
        for (int j = 0; j < 25; ++j) w[j] = wr[j];
    }
    if (tid < TT) { hs[tid] = 0.f; cs[tid] = 0.f; }
    __syncthreads();
    for (int s = 0; s < LQ_; ++s) {
        if (tid < G4) {
            const float4* hv4 = (const float4*)hs;
            float a0 = 0.f, a1 = 0.f, a2 = 0.f, a3 = 0.f;
            #pragma unroll
            for (int j = 0; j < 25; ++j) {
                float4 hv = hv4[j];
                a0 += hv.x * w[j].x; a1 += hv.y * w[j].y;
                a2 += hv.z * w[j].z; a3 += hv.w * w[j].w;
            }
            gs[tid] = xw[((long)b * LQ_ + s) * G4 + tid] + (a0 + a1) + (a2 + a3);
        }
        __syncthreads();
        if (tid < TT) {
            float ci = sigm(gs[TT + tid]) * cs[tid] + sigm(gs[tid]) * tanhf(gs[2 * TT + tid]);
            float hi = sigm(gs[3 * TT + tid]) * tanhf(ci);
            cs[tid] = ci;
            hs[tid] = hi;
            qh_emb[((long)b * LQ_ + s) * TT + tid] = hi;
            if (s == LQ_ - 1) qnode[b * TT + tid] = hi;
        }
        __syncthreads();
    }
}

// ---------------------------------------------------------------- generic 100x100 linear
// Y[r,:] = act( X[gidx?gidx[r]:r, :] @ W.T + bias*bscale[r] + add[r,:] )
__global__ __launch_bounds__(256)
void lin100_kernel(const float* __restrict__ Xbase, const int* __restrict__ gidx,
                   const float* __restrict__ W, const float* __restrict__ bias,
                   const float* __restrict__ add, const float* __restrict__ bscale,
                   float* __restrict__ Y, int rows, int relu) {
    const int RPB = 64;
    __shared__ float Wl[TT * 101];
    __shared__ float Xl[RPB * 101];
    __shared__ float bl[TT];
    int tid = threadIdx.x;
    for (int i = tid; i < TT * TT; i += 256) Wl[(i / TT) * 101 + (i % TT)] = W[i];
    for (int i = tid; i < TT; i += 256) bl[i] = bias[i];
    long r0 = (long)blockIdx.x * RPB;
    int nr = (int)((rows - r0) < RPB ? (rows - r0) : RPB);
    for (int i = tid; i < RPB * TT; i += 256) {
        int r = i / TT, k = i % TT;
        float v = 0.f;
        if (r < nr) {
            long rr = r0 + r;
            long src = gidx ? ((long)gidx[rr] * TT + k) : (rr * TT + k);
            v = Xbase[src];
        }
        Xl[r * 101 + k] = v;
    }
    __syncthreads();
    for (int it = tid; it < (RPB / 2) * 25; it += 256) {
        int rp = it & 31, gq = it >> 5;
        int r = rp * 2, t0 = gq * 4;
        float a00 = 0, a01 = 0, a02 = 0, a03 = 0, a10 = 0, a11 = 0, a12 = 0, a13 = 0;
        const float* x0 = &Xl[r * 101];
        const float* x1 = &Xl[(r + 1) * 101];
        #pragma unroll 4
        for (int k = 0; k < TT; ++k) {
            float xa = x0[k], xb = x1[k];
            float w0 = Wl[(t0 + 0) * 101 + k];
            float w1 = Wl[(t0 + 1) * 101 + k];
            float w2 = Wl[(t0 + 2) * 101 + k];
            float w3 = Wl[(t0 + 3) * 101 + k];
            a00 += xa * w0; a01 += xa * w1; a02 += xa * w2; a03 += xa * w3;
            a10 += xb * w0; a11 += xb * w1; a12 += xb * w2; a13 += xb * w3;
        }
        float acc[2][4] = {{a00, a01, a02, a03}, {a10, a11, a12, a13}};
        #pragma unroll
        for (int q = 0; q < 2; ++q) {
            if (r + q >= nr) break;
            long rr = r0 + r + q;
            float bsc = bscale ? bscale[rr] : 1.f;
            #pragma unroll
            for (int j = 0; j < 4; ++j) {
                float v = acc[q][j] + bl[t0 + j] * bsc;
                if (add) v += add[rr * TT + t0 + j];
                if (relu) v = fmaxf(v, 0.f);
                Y[rr * TT + t0 + j] = v;
            }
        }
    }
}

// ---------------------------------------------------------------- compose: C = A @ B, cb = A@ab + bb
__global__ __launch_bounds__(128)
void compose_kernel(const float* __restrict__ A, const float* __restrict__ B,
                    const float* __restrict__ ab, const float* __restrict__ bb,
                    float* __restrict__ C, float* __restrict__ cb) {
    int i = blockIdx.x, j = threadIdx.x;
    __shared__ float arow[TT];
    if (j < TT) arow[j] = A[i * TT + j];
    __syncthreads();
    if (j < TT) {
        float acc = 0.f;
        for (int k = 0; k < TT; ++k) acc += arow[k] * B[k * TT + j];
        C[i * TT + j] = acc;
    }
    if (j == 0) {
        float acc = bb[i];
        for (int k = 0; k < TT; ++k) acc += arow[k] * ab[k];
        cb[i] = acc;
    }
}

// ---------------------------------------------------------------- row gather (float4)
__global__ void gather_rows_kernel(const float* __restrict__ table, const int* __restrict__ idx,
                                   float* __restrict__ out, int rows) {
    long i = (long)blockIdx.x * 256 + threadIdx.x;
    if (i < (long)rows * 25) {
        long r = i / 25; int q = (int)(i % 25);
        ((float4*)out)[r * 25 + q] = ((const float4*)table)[(long)idx[r] * 25 + q];
    }
}

// ---------------------------------------------------------------- Wsc (fused sim/softmax/att), gathered facts
__global__ __launch_bounds__(256)
void wsc_kernel(const float* __restrict__ qh_emb, const int* __restrict__ qtext,
                const float* __restrict__ ent_f, const int* __restrict__ rel,
                float* __restrict__ Wsc) {
    int b = blockIdx.x >> 4;
    int chunk = blockIdx.x & 15;
    __shared__ __align__(16) float qh[LQ_ * TT];
    __shared__ float msk[LQ_];
    for (int i = threadIdx.x; i < LQ_ * TT; i += 256) qh[i] = qh_emb[(long)b * LQ_ * TT + i];
    for (int i = threadIdx.x; i < LQ_; i += 256)
        msk[i] = (qtext[b * LQ_ + i] != 0) ? 0.f : VERY_NEG_;
    __syncthreads();
    int f = chunk * 256 + threadIdx.x;
    if (f >= FF) return;
    long bf = (long)b * FF + f;
    const float4* fr4 = (const float4*)(ent_f + (long)rel[bf] * TT);
    float sim[LQ_];
    #pragma unroll
    for (int l = 0; l < LQ_; ++l) sim[l] = 0.f;
    for (int kq = 0; kq < 25; ++kq) {
        float4 x = fr4[kq];
        #pragma unroll
        for (int l = 0; l < LQ_; ++l) {
            float4 q = ((const float4*)(qh + l * TT))[kq];
            sim[l] += x.x * q.x + x.y * q.y + x.z * q.z + x.w * q.w;
        }
    }
    float mx = -INFINITY;
    #pragma unroll
    for (int l = 0; l < LQ_; ++l) {
        sim[l] *= 0.1f;  // /sqrt(100)
        mx = fmaxf(mx, sim[l] + msk[l]);
    }
    float ssum = 0.f, wsum = 0.f;
    #pragma unroll
    for (int l = 0; l < LQ_; ++l) {
        float p = expf(sim[l] + msk[l] - mx);
        ssum += p;
        wsum += p * sim[l];
    }
    Wsc[bf] = wsum / ssum;
}

// ---------------------------------------------------------------- row max over facts
__global__ __launch_bounds__(256)
void rowmax_kernel(const float* __restrict__ Wsc, float* __restrict__ bmax) {
    int b = blockIdx.x, tid = threadIdx.x;
    __shared__ float red[256];
    float m = -INFINITY;
    for (int f = tid; f < FF; f += 256) m = fmaxf(m, Wsc[(long)b * FF + f]);
    red[tid] = m;
    __syncthreads();
    for (int s = 128; s; s >>= 1) {
        if (tid < s) red[tid] = fmaxf(red[tid], red[tid + s]);
        __syncthreads();
    }
    if (tid == 0) bmax[b] = red[0];
}

// ---------------------------------------------------------------- W_tilde + scatter e2f_softmax + tail counts
__global__ __launch_bounds__(256)
void wtilde_kernel(const float* __restrict__ Wsc, const float* __restrict__ bmax,
                   const int* __restrict__ head, const int* __restrict__ tail,
                   float* __restrict__ W_tilde, float* __restrict__ e2f_sm,
                   float* __restrict__ cnt) {
    int idx = blockIdx.x * 256 + threadIdx.x;
    if (idx >= BB * FF) return;
    int b = idx / FF;
    float wt = expf(Wsc[idx] - bmax[b]);
    W_tilde[idx] = wt;
    atomicAdd(&e2f_sm[(long)b * EE + head[idx]], wt);
    atomicAdd(&cnt[(long)b * EE + tail[idx]], 1.f);
}

// ---------------------------------------------------------------- per-layer tiny: q2e_vec + cvecs
__global__ __launch_bounds__(128)
void qvec_kernel(const float* __restrict__ qnode,
                 const float* __restrict__ q2eW, const float* __restrict__ q2eb,
                 const float* __restrict__ e2eW, const float* __restrict__ e2eb,
                 const float* __restrict__ e2qW, const float* __restrict__ e2qb,
                 float* __restrict__ q2e_vec, float* __restrict__ cvec_e2e,
                 float* __restrict__ cvec_e2q) {
    int b = blockIdx.x, t = threadIdx.x;
    __shared__ float qn[TT], qv[TT];
    if (t < TT) qn[t] = qnode[b * TT + t];
    __syncthreads();
    if (t < TT) {
        float acc = q2eb[t];
        for (int k = 0; k < TT; ++k) acc += qn[k] * q2eW[t * TT + k];
        qv[t] = acc;
        q2e_vec[b * TT + t] = acc;
    }
    __syncthreads();
    if (t < TT) {
        float a1 = e2eb[t], a2 = e2qb[t];
        for (int k = 0; k < TT; ++k) {
            a1 += qv[k] * e2eW[(long)t * 300 + TT + k];
            a2 += qv[k] * e2qW[(long)t * 300 + TT + k];
        }
        cvec_e2e[b * TT + t] = a1;
        cvec_e2q[b * TT + t] = a2;
    }
}

// ---------------------------------------------------------------- per-fact norm + pagerank scatter
__global__ __launch_bounds__(256)
void norm_kernel(const float* __restrict__ W_tilde, const float* __restrict__ pr,
                 const float* __restrict__ e2f_sm, const int* __restrict__ head,
                 const int* __restrict__ tail, float* __restrict__ norm,
                 float* __restrict__ pr_acc) {
    int idx = blockIdx.x * 256 + threadIdx.x;
    if (idx >= BB * FF) return;
    int b = idx / FF;
    int h = head[idx];
    float n = W_tilde[idx] * pr[(long)b * EE + h] / fmaxf(e2f_sm[(long)b * EE + h], EPS_);
    norm[idx] = n;
    if (n != 0.f) atomicAdd(&pr_acc[(long)b * EE + tail[idx]], n);
}

// ---------------------------------------------------------------- e2f elementwise: relu(kbs[rel] + kbh[head])*norm -> scatter tail
__global__ __launch_bounds__(256)
void e2f_elem_kernel(const float* __restrict__ ent_kbs, const float* __restrict__ kbh,
                     const float* __restrict__ norm, const int* __restrict__ rel,
                     const int* __restrict__ head, const int* __restrict__ tail,
                     float* __restrict__ eacc) {
    long idx = (long)blockIdx.x * 256 + threadIdx.x;
    if (idx >= (long)BB * FF * 25) return;
    int q = (int)(idx % 25);
    long bf = idx / 25;
    int b = (int)(bf / FF);
    float n = norm[bf];
    if (n == 0.f) return;
    float4 s = ((const float4*)ent_kbs)[(long)rel[bf] * 25 + q];
    float4 kh = ((const float4*)kbh)[((long)b * EE + head[bf]) * 25 + q];
    float* dst = eacc + ((long)b * EE + tail[bf]) * TT + q * 4;
    atomicAdd(dst + 0, fmaxf(s.x + kh.x, 0.f) * n);
    atomicAdd(dst + 1, fmaxf(s.y + kh.y, 0.f) * n);
    atomicAdd(dst + 2, fmaxf(s.z + kh.z, 0.f) * n);
    atomicAdd(dst + 3, fmaxf(s.w + kh.w, 0.f) * n);
}

// ---------------------------------------------------------------- pagerank update
__global__ void pr_update_kernel(const float* __restrict__ pr_acc, float* __restrict__ pr,
                                 float* __restrict__ out2) {
    int i = blockIdx.x * 256 + threadIdx.x;
    if (i < BB * EE) {
        float v = 0.8f * pr_acc[i] + 0.2f * pr[i];
        pr[i] = v;
        if (out2) out2[i] = v;
    }
}

// ---------------------------------------------------------------- weighted reductions s1,s3,prsum (parallel)
#define RCH 50
__global__ __launch_bounds__(128)
void reduce_kernel(const float* __restrict__ pr, const float* __restrict__ ent,
                   const float* __restrict__ f2e, float* __restrict__ s1,
                   float* __restrict__ s3, float* __restrict__ prsum) {
    int b = blockIdx.x / (EE / RCH), ch = blockIdx.x % (EE / RCH);
    int e0 = ch * RCH, tid = threadIdx.x;
    __shared__ float prl[RCH];
    if (tid < RCH) prl[tid] = pr[(long)b * EE + e0 + tid];
    __syncthreads();
    if (tid == 0) {
        float s = 0.f;
        for (int e = 0; e < RCH; ++e) s += prl[e];
        if (s != 0.f) atomicAdd(&prsum[b], s);
    }
    if (tid < TT) {
        float a1 = 0.f, a3 = 0.f;
        for (int e = 0; e < RCH; ++e) {
            float p = prl[e];
            if (p != 0.f) {
                a1 += p * ent[((long)b * EE + e0 + e) * TT + tid];
                a3 += p * f2e[((long)b * EE + e0 + e) * TT + tid];
            }
        }
        atomicAdd(&s1[b * TT + tid], a1);
        atomicAdd(&s3[b * TT + tid], a3);
    }
}

// ---------------------------------------------------------------- qnode update
__global__ __launch_bounds__(128)
void qnode_kernel(const float* __restrict__ s1, const float* __restrict__ s3,
                  const float* __restrict__ prsum, const float* __restrict__ cvec_e2q,
                  const float* __restrict__ e2qW, float* __restrict__ qnode,
                  float* __restrict__ out2) {
    int b = blockIdx.x, t = threadIdx.x;
    __shared__ float s1l[TT], s3l[TT];
    if (t < TT) { s1l[t] = s1[b * TT + t]; s3l[t] = s3[b * TT + t]; }
    __syncthreads();
    if (t < TT) {
        float acc = prsum[b] * cvec_e2q[b * TT + t];
        const float* wr = e2qW + (long)t * 300;
        for (int k = 0; k < TT; ++k) acc += s1l[k] * wr[k] + s3l[k] * wr[200 + k];
        qnode[b * TT + t] = acc;
        if (out2) out2[b * TT + t] = acc;
    }
}

// ---------------------------------------------------------------- e2e: relu(ent@W1.T + f2e@W3.T + cvec)
__global__ __launch_bounds__(256)
void e2e_kernel(const float* __restrict__ ent, const float* __restrict__ f2e,
                const float* __restrict__ W, const float* __restrict__ cvec,
                float* __restrict__ out) {
    const int RPB = 32;
    __shared__ float W1[TT * 101], W3[TT * 101];
    __shared__ float X1[RPB * 101], X3[RPB * 101];
    int tid = threadIdx.x;
    for (int i = tid; i < TT * TT; i += 256) {
        int t = i / TT, k = i % TT;
        W1[t * 101 + k] = W[(long)t * 300 + k];
        W3[t * 101 + k] = W[(long)t * 300 + 200 + k];
    }
    long r0 = (long)blockIdx.x * RPB;
    for (int i = tid; i < RPB * TT; i += 256) {
        int r = i / TT, k = i % TT;
        X1[r * 101 + k] = ent[(r0 + r) * TT + k];
        X3[r * 101 + k] = f2e[(r0 + r) * TT + k];
    }
    __syncthreads();
    for (int it = tid; it < 16 * 25; it += 256) {
        int rp = it & 15, gq = it >> 4;
        int r = rp * 2, t0 = gq * 4;
        float a00 = 0, a01 = 0, a02 = 0, a03 = 0, a10 = 0, a11 = 0, a12 = 0, a13 = 0;
        const float* x0 = &X1[r * 101];
        const float* x1 = &X1[(r + 1) * 101];
        #pragma unroll 4
        for (int k = 0; k < TT; ++k) {
            float xa = x0[k], xb = x1[k];
            float w0 = W1[(t0 + 0) * 101 + k];
            float w1 = W1[(t0 + 1) * 101 + k];
            float w2 = W1[(t0 + 2) * 101 + k];
            float w3 = W1[(t0 + 3) * 101 + k];
            a00 += xa * w0; a01 += xa * w1; a02 += xa * w2; a03 += xa * w3;
            a10 += xb * w0; a11 += xb * w1; a12 += xb * w2; a13 += xb * w3;
        }
        const float* y0 = &X3[r * 101];
        const float* y1 = &X3[(r + 1) * 101];
        #pragma unroll 4
        for (int k = 0; k < TT; ++k) {
            float xa = y0[k], xb = y1[k];
            float w0 = W3[(t0 + 0) * 101 + k];
            float w1 = W3[(t0 + 1) * 101 + k];
            float w2 = W3[(t0 + 2) * 101 + k];
            float w3 = W3[(t0 + 3) * 101 + k];
            a00 += xa * w0; a01 += xa * w1; a02 += xa * w2; a03 += xa * w3;
            a10 += xb * w0; a11 += xb * w1; a12 += xb * w2; a13 += xb * w3;
        }
        float acc[2][4] = {{a00, a01, a02, a03}, {a10, a11, a12, a13}};
        #pragma unroll
        for (int q = 0; q < 2; ++q) {
            long rr = r0 + r + q;
            int bq = (int)(rr / EE);
            #pragma unroll
            for (int j = 0; j < 4; ++j) {
                float v = acc[q][j] + cvec[bq * TT + t0 + j];
                out[rr * TT + t0 + j] = fmaxf(v, 0.f);
            }
        }
    }
}

// ================================================================ host
extern "C" void kernel_launch(void* const* d_in, const int* in_sizes, int n_in,
                              void* d_out, int out_size, void* d_ws, size_t ws_size,
                              hipStream_t stream) {
    const float* word_emb   = (const float*)d_in[0];
    const float* entity_emb = (const float*)d_in[1];
    const float* ent_W      = (const float*)d_in[2];
    const float* ent_b      = (const float*)d_in[3];
    const float* lstm_Wih   = (const float*)d_in[4];
    const float* lstm_Whh   = (const float*)d_in[5];
    const float* lstm_bih   = (const float*)d_in[6];
    const float* lstm_bhh   = (const float*)d_in[7];
    const float* q2e_W      = (const float*)d_in[8];
    const float* q2e_b      = (const float*)d_in[9];
    const float* e2q_W      = (const float*)d_in[10];
    const float* e2q_b      = (const float*)d_in[11];
    const float* e2e_W      = (const float*)d_in[12];
    const float* e2e_b      = (const float*)d_in[13];
    const float* kbh_W      = (const float*)d_in[14];
    const float* kbh_b      = (const float*)d_in[15];
    const float* kbt_W      = (const float*)d_in[16];
    const float* kbt_b      = (const float*)d_in[17];
    const float* kbs_W      = (const float*)d_in[18];
    const float* kbs_b      = (const float*)d_in[19];
    const float* q2e_adj    = (const float*)d_in[20];
    const int* query_text   = (const int*)d_in[21];
    const int* local_entity = (const int*)d_in[22];
    const int* kb_fact_rel  = (const int*)d_in[23];
    const int* head_idx     = (const int*)d_in[24];
    const int* tail_idx     = (const int*)d_in[25];
    float* out = (float*)d_out;

    float* w = (float*)d_ws;
    size_t off = 0;
    auto alloc = [&](size_t n) {
        float* p = w + off;
        off += (n + 255) & ~(size_t)255;
        return p;
    };
    float* ent_f    = alloc((size_t)EV_ * TT);       // vocab table, ent linear
    float* ent_kbs  = alloc((size_t)EV_ * TT);       // vocab table, kbs∘ent (per layer)
    float* entA     = alloc((size_t)BB * EE * TT);
    float* entB     = alloc((size_t)BB * EE * TT);
    float* kbh      = alloc((size_t)BB * EE * TT);   // aliased as f2e after e2f
    float* kbs_e    = alloc((size_t)BB * EE * TT);
    float* eacc     = alloc((size_t)BB * EE * TT);   // contiguous with pr_acc for one memset
    float* pr_acc   = alloc((size_t)BB * EE);
    float* xw       = alloc((size_t)BB * LQ_ * G4);
    float* qh_emb   = alloc((size_t)BB * LQ_ * TT);
    float* WihT     = alloc((size_t)G4 * EMB_);
    float* Wsc      = alloc((size_t)BB * FF);
    float* W_tilde  = alloc((size_t)BB * FF);
    float* normf    = alloc((size_t)BB * FF);
    float* bmaxb    = alloc(BB);
    float* e2f_sm   = alloc((size_t)BB * EE);        // contiguous with cnt
    float* cnt      = alloc((size_t)BB * EE);
    float* pr       = alloc((size_t)BB * EE);
    float* qnode    = alloc((size_t)BB * TT);
    float* q2e_vec  = alloc((size_t)BB * TT);
    float* cvec_e2e = alloc((size_t)BB * TT);
    float* cvec_e2q = alloc((size_t)BB * TT);
    float* s1       = alloc((size_t)BB * TT);        // s1,s3,prsum contiguous
    float* s3       = alloc((size_t)BB * TT);
    float* prsum    = alloc(BB);
    float* Ckbs     = alloc((size_t)TT * TT);
    float* cbkbs    = alloc(TT);
    float* f2e = kbh;  // alias: kbh dead after e2f

    // ---- LSTM path
    transpose_kernel<<<(G4 * EMB_ + 255) / 256, 256, 0, stream>>>(lstm_Wih, WihT, G4, EMB_);
    xw_kernel<<<BB * LQ_, 256, 0, stream>>>(word_emb, query_text, WihT, lstm_bih, lstm_bhh, xw);
    lstm_kernel<<<BB, 512, 0, stream>>>(xw, lstm_Whh, qh_emb, qnode);

    // ---- vocab ent table + gathered local entity embeddings
    lin100_kernel<<<(EV_ + 63) / 64, 256, 0, stream>>>(entity_emb, nullptr, ent_W, ent_b,
                                                       nullptr, nullptr, ent_f, EV_, 0);
    gather_rows_kernel<<<(BB * EE * 25 + 255) / 256, 256, 0, stream>>>(ent_f, local_entity,
                                                                       entA, BB * EE);

    // ---- attention scores -> W_tilde, e2f_softmax, counts
    wsc_kernel<<<BB * 16, 256, 0, stream>>>(qh_emb, query_text, ent_f, kb_fact_rel, Wsc);
    rowmax_kernel<<<BB, 256, 0, stream>>>(Wsc, bmaxb);
    hipMemsetAsync(e2f_sm, 0, (size_t)2 * BB * EE * 4, stream);
    wtilde_kernel<<<(BB * FF + 255) / 256, 256, 0, stream>>>(Wsc, bmaxb, head_idx, tail_idx,
                                                             W_tilde, e2f_sm, cnt);
    hipMemcpyAsync(pr, q2e_adj, (size_t)BB * EE * 4, hipMemcpyDeviceToDevice, stream);

    // ---- GNN layers
    for (int i = 0; i < 2; ++i) {
        const float* ent_in = i ? entB : entA;
        float* ent_out = i ? out : entB;
        qvec_kernel<<<BB, 128, 0, stream>>>(qnode, q2e_W + i * TT * TT, q2e_b + i * TT,
                                            e2e_W + i * TT * 300, e2e_b + i * TT,
                                            e2q_W + i * TT * 300, e2q_b + i * TT,
                                            q2e_vec, cvec_e2e, cvec_e2q);
        // kbs∘ent composed to vocab table
        compose_kernel<<<TT, 128, 0, stream>>>(kbs_W + i * TT * TT, ent_W, ent_b,
                                               kbs_b + i * TT, Ckbs, cbkbs);
        lin100_kernel<<<(EV_ + 63) / 64, 256, 0, stream>>>(entity_emb, nullptr, Ckbs, cbkbs,
                                                           nullptr, nullptr, ent_kbs, EV_, 0);
        lin100_kernel<<<(BB * EE) / 64, 256, 0, stream>>>(ent_in, nullptr, kbh_W + i * TT * TT,
                                                          kbh_b + i * TT, nullptr, nullptr,
                                                          kbh, BB * EE, 0);
        lin100_kernel<<<(BB * EE) / 64, 256, 0, stream>>>(ent_in, nullptr, kbs_W + i * TT * TT,
                                                          kbs_b + i * TT, nullptr, nullptr,
                                                          kbs_e, BB * EE, 0);
        hipMemsetAsync(eacc, 0, ((size_t)BB * EE * TT + BB * EE) * 4, stream);  // eacc+pr_acc
        norm_kernel<<<(BB * FF + 255) / 256, 256, 0, stream>>>(W_tilde, pr, e2f_sm, head_idx,
                                                               tail_idx, normf, pr_acc);
        e2f_elem_kernel<<<(int)(((long)BB * FF * 25 + 255) / 256), 256, 0, stream>>>(
            ent_kbs, kbh, normf, kb_fact_rel, head_idx, tail_idx, eacc);
        // f2e = relu(kbs_e + eacc@kbt.T + kbt_b*cnt)   (f2e aliases kbh)
        lin100_kernel<<<(BB * EE) / 64, 256, 0, stream>>>(eacc, nullptr, kbt_W + i * TT * TT,
                                                          kbt_b + i * TT, kbs_e, cnt,
                                                          f2e, BB * EE, 1);
        pr_update_kernel<<<(BB * EE + 255) / 256, 256, 0, stream>>>(
            pr_acc, pr, (i == 1) ? out + 6406400 : nullptr);
        hipMemsetAsync(s1, 0, (size_t)(2 * BB * TT + BB) * 4, stream);  // s1,s3,prsum contiguous
        reduce_kernel<<<BB * (EE / RCH), 128, 0, stream>>>(pr, ent_in, f2e, s1, s3, prsum);
        qnode_kernel<<<BB, 128, 0, stream>>>(s1, s3, prsum, cvec_e2q, e2q_W + i * TT * 300,
                                             qnode, (i == 1) ? out + 6400000 : nullptr);
        e2e_kernel<<<(BB * EE) / 32, 256, 0, stream>>>(ent_in, f2e, e2e_W + i * TT * 300,
                                                       cvec_e2e, ent_out);
    }
}

// Round 4
// 1510.277 us; speedup vs baseline: 1.7788x; 1.0004x over previous
//
#include <hip/hip_runtime.h>
#include <hip/hip_bf16.h>

#define BB 64
#define EE 1000
#define FF 4000
#define LQ_ 30
#define TT 100
#define EMB_ 300
#define G4 400
#define EV_ 50007
#define VERY_NEG_ (-100000000000.0f)
#define EPS_ 1e-10f

typedef __attribute__((ext_vector_type(8))) short bf16x8;
typedef __attribute__((ext_vector_type(4))) float f32x4;

__device__ __forceinline__ float sigm(float x) { return 1.0f / (1.0f + expf(-x)); }

__device__ __forceinline__ short f2bf(float v) {
    __hip_bfloat16 h = __float2bfloat16(v);
    return *(short*)&h;
}

// ---------------------------------------------------------------- transpose
__global__ void transpose_kernel(const float* __restrict__ in, float* __restrict__ out,
                                 int rows, int cols) {
    int i = blockIdx.x * 256 + threadIdx.x;
    if (i < rows * cols) {
        int r = i / cols, c = i % cols;
        out[c * rows + r] = in[i];
    }
}

// ---------------------------------------------------------------- xw = word_emb[qtext] @ Wih.T + bih + bhh
__global__ __launch_bounds__(256)
void xw_kernel(const float* __restrict__ word_emb, const int* __restrict__ qtext,
               const float* __restrict__ WihT, const float* __restrict__ bih,
               const float* __restrict__ bhh, float* __restrict__ xw) {
    int bs = blockIdx.x;  // b*LQ + s
    __shared__ float x[EMB_];
    int wid = qtext[bs];
    for (int i = threadIdx.x; i < EMB_; i += 256) x[i] = word_emb[(long)wid * EMB_ + i];
    __syncthreads();
    for (int g = threadIdx.x; g < G4; g += 256) {
        float acc = bih[g] + bhh[g];
        #pragma unroll 4
        for (int k = 0; k < EMB_; ++k) acc += x[k] * WihT[k * G4 + g];
        xw[(long)bs * G4 + g] = acc;
    }
}

// ---------------------------------------------------------------- LSTM: weights in registers
__global__ __launch_bounds__(512)
void lstm_kernel(const float* __restrict__ xw, const float* __restrict__ Whh,
                 float* __restrict__ qh_emb, float* __restrict__ qnode) {
    int b = blockIdx.x, tid = threadIdx.x;
    __shared__ __align__(16) float hs[TT];
    __shared__ float cs[TT];
    __shared__ float gs[G4];
    float4 w[25];
    if (tid < G4) {
        const float4* wr = (const float4*)(Whh + (long)tid * TT);
        #pragma unroll
        for (int j = 0; j < 25; ++j) w[j] = wr[j];
    }
    if (tid < TT) { hs[tid] = 0.f; cs[tid] = 0.f; }
    __syncthreads();
    for (int s = 0; s < LQ_; ++s) {
        if (tid < G4) {
            const float4* hv4 = (const float4*)hs;
            float a0 = 0.f, a1 = 0.f, a2 = 0.f, a3 = 0.f;
            #pragma unroll
            for (int j = 0; j < 25; ++j) {
                float4 hv = hv4[j];
                a0 += hv.x * w[j].x; a1 += hv.y * w[j].y;
                a2 += hv.z * w[j].z; a3 += hv.w * w[j].w;
            }
            gs[tid] = xw[((long)b * LQ_ + s) * G4 + tid] + (a0 + a1) + (a2 + a3);
        }
        __syncthreads();
        if (tid < TT) {
            float ci = sigm(gs[TT + tid]) * cs[tid] + sigm(gs[tid]) * tanhf(gs[2 * TT + tid]);
            float hi = sigm(gs[3 * TT + tid]) * tanhf(ci);
            cs[tid] = ci;
            hs[tid] = hi;
            qh_emb[((long)b * LQ_ + s) * TT + tid] = hi;
            if (s == LQ_ - 1) qnode[b * TT + tid] = hi;
        }
        __syncthreads();
    }
}

// ---------------------------------------------------------------- MFMA bf16 GEMM (K=100, N=100)
// Y[r,:] = act( X[gidx?gidx[r]:r, :] @ W.T + bias*bscale[r] + add_mat[r,:] + cvec[r/EE,:] )
__global__ __launch_bounds__(256)
void gemm_bf16_kernel(const float* __restrict__ X, const int* __restrict__ gidx,
                      const float* __restrict__ W, int w_stride,
                      const float* __restrict__ bias, const float* __restrict__ bscale,
                      const float* __restrict__ add_mat, const float* __restrict__ cvec,
                      float* __restrict__ Y, int rows, int relu) {
    __shared__ __align__(16) short sX[64 * 136];   // 64 rows x 128 k (pad 136)
    __shared__ __align__(16) short sW[112 * 136];  // 112 t  x 128 k (pad 136)
    int tid = threadIdx.x;
    long r0 = (long)blockIdx.x * 64;
    // stage W (f32 -> bf16), zero-pad t>=100, k>=100
    for (int i = tid; i < 112 * 128; i += 256) {
        int t = i >> 7, k = i & 127;
        float v = (t < TT && k < TT) ? W[(long)t * w_stride + k] : 0.f;
        sW[t * 136 + k] = f2bf(v);
    }
    // stage X
    for (int i = tid; i < 64 * 128; i += 256) {
        int r = i >> 7, k = i & 127;
        long rr = r0 + r;
        float v = 0.f;
        if (rr < rows && k < TT) {
            long src = gidx ? ((long)gidx[rr] * TT + k) : (rr * TT + k);
            v = X[src];
        }
        sX[r * 136 + k] = f2bf(v);
    }
    __syncthreads();
    int lane = tid & 63;
    int wv = tid >> 6;               // wave id: rows [wv*16, wv*16+16)
    int arow = lane & 15, agrp = lane >> 4;
    f32x4 acc[7];
    #pragma unroll
    for (int n = 0; n < 7; ++n) acc[n] = (f32x4){0.f, 0.f, 0.f, 0.f};
    #pragma unroll
    for (int kk = 0; kk < 4; ++kk) {
        bf16x8 a = *(const bf16x8*)&sX[(wv * 16 + arow) * 136 + kk * 32 + agrp * 8];
        #pragma unroll
        for (int n = 0; n < 7; ++n) {
            bf16x8 b = *(const bf16x8*)&sW[(n * 16 + arow) * 136 + kk * 32 + agrp * 8];
            acc[n] = __builtin_amdgcn_mfma_f32_16x16x32_bf16(a, b, acc[n], 0, 0, 0);
        }
    }
    // epilogue: D col = lane&15 (-> t), row = (lane>>4)*4 + reg
    int t_lo = lane & 15;
    int r_hi = (lane >> 4) * 4;
    #pragma unroll
    for (int n = 0; n < 7; ++n) {
        int t = n * 16 + t_lo;
        if (t >= TT) continue;
        #pragma unroll
        for (int j = 0; j < 4; ++j) {
            long gr = r0 + wv * 16 + r_hi + j;
            if (gr >= rows) continue;
            float v = acc[n][j];
            if (bias) v += bias[t] * (bscale ? bscale[gr] : 1.f);
            if (add_mat) v += add_mat[gr * TT + t];
            if (cvec) v += cvec[(int)(gr / EE) * TT + t];
            if (relu) v = fmaxf(v, 0.f);
            Y[gr * TT + t] = v;
        }
    }
}

// ---------------------------------------------------------------- compose: C = A @ B, cb = A@ab + bb
__global__ __launch_bounds__(128)
void compose_kernel(const float* __restrict__ A, const float* __restrict__ B,
                    const float* __restrict__ ab, const float* __restrict__ bb,
                    float* __restrict__ C, float* __restrict__ cb) {
    int i = blockIdx.x, j = threadIdx.x;
    __shared__ float arow[TT];
    if (j < TT) arow[j] = A[i * TT + j];
    __syncthreads();
    if (j < TT) {
        float acc = 0.f;
        for (int k = 0; k < TT; ++k) acc += arow[k] * B[k * TT + j];
        C[i * TT + j] = acc;
    }
    if (j == 0) {
        float acc = bb[i];
        for (int k = 0; k < TT; ++k) acc += arow[k] * ab[k];
        cb[i] = acc;
    }
}

// ---------------------------------------------------------------- row gather (float4)
__global__ void gather_rows_kernel(const float* __restrict__ table, const int* __restrict__ idx,
                                   float* __restrict__ out, int rows) {
    long i = (long)blockIdx.x * 256 + threadIdx.x;
    if (i < (long)rows * 25) {
        long r = i / 25; int q = (int)(i % 25);
        ((float4*)out)[r * 25 + q] = ((const float4*)table)[(long)idx[r] * 25 + q];
    }
}

// ---------------------------------------------------------------- Wsc (fused sim/softmax/att), gathered facts
__global__ __launch_bounds__(256)
void wsc_kernel(const float* __restrict__ qh_emb, const int* __restrict__ qtext,
                const float* __restrict__ ent_f, const int* __restrict__ rel,
                float* __restrict__ Wsc) {
    int b = blockIdx.x >> 4;
    int chunk = blockIdx.x & 15;
    __shared__ __align__(16) float qh[LQ_ * TT];
    __shared__ float msk[LQ_];
    for (int i = threadIdx.x; i < LQ_ * TT; i += 256) qh[i] = qh_emb[(long)b * LQ_ * TT + i];
    for (int i = threadIdx.x; i < LQ_; i += 256)
        msk[i] = (qtext[b * LQ_ + i] != 0) ? 0.f : VERY_NEG_;
    __syncthreads();
    int f = chunk * 256 + threadIdx.x;
    if (f >= FF) return;
    long bf = (long)b * FF + f;
    const float4* fr4 = (const float4*)(ent_f + (long)rel[bf] * TT);
    float sim[LQ_];
    #pragma unroll
    for (int l = 0; l < LQ_; ++l) sim[l] = 0.f;
    for (int kq = 0; kq < 25; ++kq) {
        float4 x = fr4[kq];
        #pragma unroll
        for (int l = 0; l < LQ_; ++l) {
            float4 q = ((const float4*)(qh + l * TT))[kq];
            sim[l] += x.x * q.x + x.y * q.y + x.z * q.z + x.w * q.w;
        }
    }
    float mx = -INFINITY;
    #pragma unroll
    for (int l = 0; l < LQ_; ++l) {
        sim[l] *= 0.1f;  // /sqrt(100)
        mx = fmaxf(mx, sim[l] + msk[l]);
    }
    float ssum = 0.f, wsum = 0.f;
    #pragma unroll
    for (int l = 0; l < LQ_; ++l) {
        float p = expf(sim[l] + msk[l] - mx);
        ssum += p;
        wsum += p * sim[l];
    }
    Wsc[bf] = wsum / ssum;
}

// ---------------------------------------------------------------- row max over facts
__global__ __launch_bounds__(256)
void rowmax_kernel(const float* __restrict__ Wsc, float* __restrict__ bmax) {
    int b = blockIdx.x, tid = threadIdx.x;
    __shared__ float red[256];
    float m = -INFINITY;
    for (int f = tid; f < FF; f += 256) m = fmaxf(m, Wsc[(long)b * FF + f]);
    red[tid] = m;
    __syncthreads();
    for (int s = 128; s; s >>= 1) {
        if (tid < s) red[tid] = fmaxf(red[tid], red[tid + s]);
        __syncthreads();
    }
    if (tid == 0) bmax[b] = red[0];
}

// ---------------------------------------------------------------- W_tilde + scatter e2f_softmax + tail counts
__global__ __launch_bounds__(256)
void wtilde_kernel(const float* __restrict__ Wsc, const float* __restrict__ bmax,
                   const int* __restrict__ head, const int* __restrict__ tail,
                   float* __restrict__ W_tilde, float* __restrict__ e2f_sm,
                   float* __restrict__ cnt) {
    int idx = blockIdx.x * 256 + threadIdx.x;
    if (idx >= BB * FF) return;
    int b = idx / FF;
    float wt = expf(Wsc[idx] - bmax[b]);
    W_tilde[idx] = wt;
    atomicAdd(&e2f_sm[(long)b * EE + head[idx]], wt);
    atomicAdd(&cnt[(long)b * EE + tail[idx]], 1.f);
}

// ---------------------------------------------------------------- per-layer tiny: q2e_vec + cvecs
__global__ __launch_bounds__(128)
void qvec_kernel(const float* __restrict__ qnode,
                 const float* __restrict__ q2eW, const float* __restrict__ q2eb,
                 const float* __restrict__ e2eW, const float* __restrict__ e2eb,
                 const float* __restrict__ e2qW, const float* __restrict__ e2qb,
                 float* __restrict__ q2e_vec, float* __restrict__ cvec_e2e,
                 float* __restrict__ cvec_e2q) {
    int b = blockIdx.x, t = threadIdx.x;
    __shared__ float qn[TT], qv[TT];
    if (t < TT) qn[t] = qnode[b * TT + t];
    __syncthreads();
    if (t < TT) {
        float acc = q2eb[t];
        for (int k = 0; k < TT; ++k) acc += qn[k] * q2eW[t * TT + k];
        qv[t] = acc;
        q2e_vec[b * TT + t] = acc;
    }
    __syncthreads();
    if (t < TT) {
        float a1 = e2eb[t], a2 = e2qb[t];
        for (int k = 0; k < TT; ++k) {
            a1 += qv[k] * e2eW[(long)t * 300 + TT + k];
            a2 += qv[k] * e2qW[(long)t * 300 + TT + k];
        }
        cvec_e2e[b * TT + t] = a1;
        cvec_e2q[b * TT + t] = a2;
    }
}

// ---------------------------------------------------------------- per-fact norm + pagerank scatter
__global__ __launch_bounds__(256)
void norm_kernel(const float* __restrict__ W_tilde, const float* __restrict__ pr,
                 const float* __restrict__ e2f_sm, const int* __restrict__ head,
                 const int* __restrict__ tail, float* __restrict__ norm,
                 float* __restrict__ pr_acc) {
    int idx = blockIdx.x * 256 + threadIdx.x;
    if (idx >= BB * FF) return;
    int b = idx / FF;
    int h = head[idx];
    float n = W_tilde[idx] * pr[(long)b * EE + h] / fmaxf(e2f_sm[(long)b * EE + h], EPS_);
    norm[idx] = n;
    if (n != 0.f) atomicAdd(&pr_acc[(long)b * EE + tail[idx]], n);
}

// ---------------------------------------------------------------- e2f elementwise: relu(kbs[rel] + kbh[head])*norm -> scatter tail
__global__ __launch_bounds__(256)
void e2f_elem_kernel(const float* __restrict__ ent_kbs, const float* __restrict__ kbh,
                     const float* __restrict__ norm, const int* __restrict__ rel,
                     const int* __restrict__ head, const int* __restrict__ tail,
                     float* __restrict__ eacc) {
    long idx = (long)blockIdx.x * 256 + threadIdx.x;
    if (idx >= (long)BB * FF * 25) return;
    int q = (int)(idx % 25);
    long bf = idx / 25;
    int b = (int)(bf / FF);
    float n = norm[bf];
    if (n == 0.f) return;
    float4 s = ((const float4*)ent_kbs)[(long)rel[bf] * 25 + q];
    float4 kh = ((const float4*)kbh)[((long)b * EE + head[bf]) * 25 + q];
    float* dst = eacc + ((long)b * EE + tail[bf]) * TT + q * 4;
    atomicAdd(dst + 0, fmaxf(s.x + kh.x, 0.f) * n);
    atomicAdd(dst + 1, fmaxf(s.y + kh.y, 0.f) * n);
    atomicAdd(dst + 2, fmaxf(s.z + kh.z, 0.f) * n);
    atomicAdd(dst + 3, fmaxf(s.w + kh.w, 0.f) * n);
}

// ---------------------------------------------------------------- pagerank update
__global__ void pr_update_kernel(const float* __restrict__ pr_acc, float* __restrict__ pr,
                                 float* __restrict__ out2) {
    int i = blockIdx.x * 256 + threadIdx.x;
    if (i < BB * EE) {
        float v = 0.8f * pr_acc[i] + 0.2f * pr[i];
        pr[i] = v;
        if (out2) out2[i] = v;
    }
}

// ---------------------------------------------------------------- weighted reductions s1,s3,prsum (parallel)
#define RCH 50
__global__ __launch_bounds__(128)
void reduce_kernel(const float* __restrict__ pr, const float* __restrict__ ent,
                   const float* __restrict__ f2e, float* __restrict__ s1,
                   float* __restrict__ s3, float* __restrict__ prsum) {
    int b = blockIdx.x / (EE / RCH), ch = blockIdx.x % (EE / RCH);
    int e0 = ch * RCH, tid = threadIdx.x;
    __shared__ float prl[RCH];
    if (tid < RCH) prl[tid] = pr[(long)b * EE + e0 + tid];
    __syncthreads();
    if (tid == 0) {
        float s = 0.f;
        for (int e = 0; e < RCH; ++e) s += prl[e];
        if (s != 0.f) atomicAdd(&prsum[b], s);
    }
    if (tid < TT) {
        float a1 = 0.f, a3 = 0.f;
        for (int e = 0; e < RCH; ++e) {
            float p = prl[e];
            if (p != 0.f) {
                a1 += p * ent[((long)b * EE + e0 + e) * TT + tid];
                a3 += p * f2e[((long)b * EE + e0 + e) * TT + tid];
            }
        }
        atomicAdd(&s1[b * TT + tid], a1);
        atomicAdd(&s3[b * TT + tid], a3);
    }
}

// ---------------------------------------------------------------- qnode update
__global__ __launch_bounds__(128)
void qnode_kernel(const float* __restrict__ s1, const float* __restrict__ s3,
                  const float* __restrict__ prsum, const float* __restrict__ cvec_e2q,
                  const float* __restrict__ e2qW, float* __restrict__ qnode,
                  float* __restrict__ out2) {
    int b = blockIdx.x, t = threadIdx.x;
    __shared__ float s1l[TT], s3l[TT];
    if (t < TT) { s1l[t] = s1[b * TT + t]; s3l[t] = s3[b * TT + t]; }
    __syncthreads();
    if (t < TT) {
        float acc = prsum[b] * cvec_e2q[b * TT + t];
        const float* wr = e2qW + (long)t * 300;
        for (int k = 0; k < TT; ++k) acc += s1l[k] * wr[k] + s3l[k] * wr[200 + k];
        qnode[b * TT + t] = acc;
        if (out2) out2[b * TT + t] = acc;
    }
}

// ================================================================ host
extern "C" void kernel_launch(void* const* d_in, const int* in_sizes, int n_in,
                              void* d_out, int out_size, void* d_ws, size_t ws_size,
                              hipStream_t stream) {
    const float* word_emb   = (const float*)d_in[0];
    const float* entity_emb = (const float*)d_in[1];
    const float* ent_W      = (const float*)d_in[2];
    const float* ent_b      = (const float*)d_in[3];
    const float* lstm_Wih   = (const float*)d_in[4];
    const float* lstm_Whh   = (const float*)d_in[5];
    const float* lstm_bih   = (const float*)d_in[6];
    const float* lstm_bhh   = (const float*)d_in[7];
    const float* q2e_W      = (const float*)d_in[8];
    const float* q2e_b      = (const float*)d_in[9];
    const float* e2q_W      = (const float*)d_in[10];
    const float* e2q_b      = (const float*)d_in[11];
    const float* e2e_W      = (const float*)d_in[12];
    const float* e2e_b      = (const float*)d_in[13];
    const float* kbh_W      = (const float*)d_in[14];
    const float* kbh_b      = (const float*)d_in[15];
    const float* kbt_W      = (const float*)d_in[16];
    const float* kbt_b      = (const float*)d_in[17];
    const float* kbs_W      = (const float*)d_in[18];
    const float* kbs_b      = (const float*)d_in[19];
    const float* q2e_adj    = (const float*)d_in[20];
    const int* query_text   = (const int*)d_in[21];
    const int* local_entity = (const int*)d_in[22];
    const int* kb_fact_rel  = (const int*)d_in[23];
    const int* head_idx     = (const int*)d_in[24];
    const int* tail_idx     = (const int*)d_in[25];
    float* out = (float*)d_out;

    float* w = (float*)d_ws;
    size_t off = 0;
    auto alloc = [&](size_t n) {
        float* p = w + off;
        off += (n + 255) & ~(size_t)255;
        return p;
    };
    float* ent_f    = alloc((size_t)EV_ * TT);       // vocab table, ent linear
    float* ent_kbs  = alloc((size_t)EV_ * TT);       // vocab table, kbs∘ent (per layer)
    float* entA     = alloc((size_t)BB * EE * TT);
    float* entB     = alloc((size_t)BB * EE * TT);
    float* kbh      = alloc((size_t)BB * EE * TT);   // aliased as f2e after e2f
    float* kbs_e    = alloc((size_t)BB * EE * TT);
    float* eacc     = alloc((size_t)BB * EE * TT);   // contiguous with pr_acc for one memset
    float* pr_acc   = alloc((size_t)BB * EE);
    float* xw       = alloc((size_t)BB * LQ_ * G4);
    float* qh_emb   = alloc((size_t)BB * LQ_ * TT);
    float* WihT     = alloc((size_t)G4 * EMB_);
    float* Wsc      = alloc((size_t)BB * FF);
    float* W_tilde  = alloc((size_t)BB * FF);
    float* normf    = alloc((size_t)BB * FF);
    float* bmaxb    = alloc(BB);
    float* e2f_sm   = alloc((size_t)BB * EE);        // contiguous with cnt
    float* cnt      = alloc((size_t)BB * EE);
    float* pr       = alloc((size_t)BB * EE);
    float* qnode    = alloc((size_t)BB * TT);
    float* q2e_vec  = alloc((size_t)BB * TT);
    float* cvec_e2e = alloc((size_t)BB * TT);
    float* cvec_e2q = alloc((size_t)BB * TT);
    float* s1       = alloc((size_t)BB * TT);        // s1,s3,prsum contiguous
    float* s3       = alloc((size_t)BB * TT);
    float* prsum    = alloc(BB);
    float* Ckbs     = alloc((size_t)TT * TT);
    float* cbkbs    = alloc(TT);
    float* f2e = kbh;  // alias: kbh dead after e2f_elem

    // ---- LSTM path
    transpose_kernel<<<(G4 * EMB_ + 255) / 256, 256, 0, stream>>>(lstm_Wih, WihT, G4, EMB_);
    xw_kernel<<<BB * LQ_, 256, 0, stream>>>(word_emb, query_text, WihT, lstm_bih, lstm_bhh, xw);
    lstm_kernel<<<BB, 512, 0, stream>>>(xw, lstm_Whh, qh_emb, qnode);

    // ---- vocab ent table + gathered local entity embeddings
    gemm_bf16_kernel<<<(EV_ + 63) / 64, 256, 0, stream>>>(
        entity_emb, nullptr, ent_W, TT, ent_b, nullptr, nullptr, nullptr, ent_f, EV_, 0);
    gather_rows_kernel<<<(BB * EE * 25 + 255) / 256, 256, 0, stream>>>(ent_f, local_entity,
                                                                       entA, BB * EE);

    // ---- attention scores -> W_tilde, e2f_softmax, counts
    wsc_kernel<<<BB * 16, 256, 0, stream>>>(qh_emb, query_text, ent_f, kb_fact_rel, Wsc);
    rowmax_kernel<<<BB, 256, 0, stream>>>(Wsc, bmaxb);
    hipMemsetAsync(e2f_sm, 0, (size_t)2 * BB * EE * 4, stream);
    wtilde_kernel<<<(BB * FF + 255) / 256, 256, 0, stream>>>(Wsc, bmaxb, head_idx, tail_idx,
                                                             W_tilde, e2f_sm, cnt);
    hipMemcpyAsync(pr, q2e_adj, (size_t)BB * EE * 4, hipMemcpyDeviceToDevice, stream);

    // ---- GNN layers
    for (int i = 0; i < 2; ++i) {
        const float* ent_in = i ? entB : entA;
        float* ent_out = i ? out : entB;
        qvec_kernel<<<BB, 128, 0, stream>>>(qnode, q2e_W + i * TT * TT, q2e_b + i * TT,
                                            e2e_W + i * TT * 300, e2e_b + i * TT,
                                            e2q_W + i * TT * 300, e2q_b + i * TT,
                                            q2e_vec, cvec_e2e, cvec_e2q);
        // kbs∘ent composed to vocab table
        compose_kernel<<<TT, 128, 0, stream>>>(kbs_W + i * TT * TT, ent_W, ent_b,
                                               kbs_b + i * TT, Ckbs, cbkbs);
        gemm_bf16_kernel<<<(EV_ + 63) / 64, 256, 0, stream>>>(
            entity_emb, nullptr, Ckbs, TT, cbkbs, nullptr, nullptr, nullptr, ent_kbs, EV_, 0);
        gemm_bf16_kernel<<<(BB * EE) / 64, 256, 0, stream>>>(
            ent_in, nullptr, kbh_W + i * TT * TT, TT, kbh_b + i * TT, nullptr, nullptr, nullptr,
            kbh, BB * EE, 0);
        gemm_bf16_kernel<<<(BB * EE) / 64, 256, 0, stream>>>(
            ent_in, nullptr, kbs_W + i * TT * TT, TT, kbs_b + i * TT, nullptr, nullptr, nullptr,
            kbs_e, BB * EE, 0);
        hipMemsetAsync(eacc, 0, ((size_t)BB * EE * TT + BB * EE) * 4, stream);  // eacc+pr_acc
        norm_kernel<<<(BB * FF + 255) / 256, 256, 0, stream>>>(W_tilde, pr, e2f_sm, head_idx,
                                                               tail_idx, normf, pr_acc);
        e2f_elem_kernel<<<(int)(((long)BB * FF * 25 + 255) / 256), 256, 0, stream>>>(
            ent_kbs, kbh, normf, kb_fact_rel, head_idx, tail_idx, eacc);
        // f2e = relu(kbs_e + eacc@kbt.T + kbt_b*cnt)   (f2e aliases kbh)
        gemm_bf16_kernel<<<(BB * EE) / 64, 256, 0, stream>>>(
            eacc, nullptr, kbt_W + i * TT * TT, TT, kbt_b + i * TT, cnt, kbs_e, nullptr,
            f2e, BB * EE, 1);
        pr_update_kernel<<<(BB * EE + 255) / 256, 256, 0, stream>>>(
            pr_acc, pr, (i == 1) ? out + 6406400 : nullptr);
        hipMemsetAsync(s1, 0, (size_t)(2 * BB * TT + BB) * 4, stream);  // s1,s3,prsum contiguous
        reduce_kernel<<<BB * (EE / RCH), 128, 0, stream>>>(pr, ent_in, f2e, s1, s3, prsum);
        qnode_kernel<<<BB, 128, 0, stream>>>(s1, s3, prsum, cvec_e2q, e2q_W + i * TT * 300,
                                             qnode, (i == 1) ? out + 6400000 : nullptr);
        // e2e = relu(ent_in@W1.T + f2e@W3.T + cvec_e2e) : two K=100 passes, tmp = eacc
        gemm_bf16_kernel<<<(BB * EE) / 64, 256, 0, stream>>>(
            ent_in, nullptr, e2e_W + i * TT * 300, 300, nullptr, nullptr, nullptr, nullptr,
            eacc, BB * EE, 0);
        gemm_bf16_kernel<<<(BB * EE) / 64, 256, 0, stream>>>(
            f2e, nullptr, e2e_W + i * TT * 300 + 200, 300, nullptr, nullptr, eacc, cvec_e2e,
            ent_out, BB * EE, 1);
    }
}

// Round 5
// 831.107 us; speedup vs baseline: 3.2325x; 1.8172x over previous
//
#include <hip/hip_runtime.h>
#include <hip/hip_bf16.h>

#define BB 64
#define EE 1000
#define FF 4000
#define LQ_ 30
#define TT 100
#define EMB_ 300
#define G4 400
#define EV_ 50007
#define VERY_NEG_ (-100000000000.0f)
#define EPS_ 1e-10f

typedef __attribute__((ext_vector_type(8))) short bf16x8;
typedef __attribute__((ext_vector_type(4))) float f32x4;

__device__ __forceinline__ float sigm(float x) { return 1.0f / (1.0f + expf(-x)); }

__device__ __forceinline__ unsigned short f2bf(float v) {
    __hip_bfloat16 h = __float2bfloat16(v);
    return *reinterpret_cast<unsigned short*>(&h);
}
__device__ __forceinline__ float bf2f(unsigned short s) {
    return __uint_as_float((unsigned)s << 16);
}

// ---------------------------------------------------------------- f32 -> bf16 bulk convert
__global__ void cvt_bf16_kernel(const float* __restrict__ in, unsigned short* __restrict__ out,
                                long n4) {
    long i = (long)blockIdx.x * 256 + threadIdx.x;
    if (i < n4) {
        float4 v = ((const float4*)in)[i];
        ushort4 o;
        o.x = f2bf(v.x); o.y = f2bf(v.y); o.z = f2bf(v.z); o.w = f2bf(v.w);
        ((ushort4*)out)[i] = o;
    }
}

// ---------------------------------------------------------------- transpose
__global__ void transpose_kernel(const float* __restrict__ in, float* __restrict__ out,
                                 int rows, int cols) {
    int i = blockIdx.x * 256 + threadIdx.x;
    if (i < rows * cols) {
        int r = i / cols, c = i % cols;
        out[c * rows + r] = in[i];
    }
}

// ---------------------------------------------------------------- xw: 4 tokens per block
__global__ __launch_bounds__(256)
void xw_kernel(const float* __restrict__ word_emb, const int* __restrict__ qtext,
               const float* __restrict__ WihT, const float* __restrict__ bih,
               const float* __restrict__ bhh, float* __restrict__ xw) {
    int bs0 = blockIdx.x * 4;
    __shared__ float x[4][EMB_];
    int tid = threadIdx.x;
    for (int i = tid; i < 4 * EMB_; i += 256) {
        int s = i / EMB_, k = i % EMB_;
        x[s][k] = word_emb[(long)qtext[bs0 + s] * EMB_ + k];
    }
    __syncthreads();
    for (int g = tid; g < G4; g += 256) {
        float b0 = bih[g] + bhh[g];
        float a0 = b0, a1 = b0, a2 = b0, a3 = b0;
        #pragma unroll 4
        for (int k = 0; k < EMB_; ++k) {
            float wv = WihT[k * G4 + g];
            a0 += x[0][k] * wv; a1 += x[1][k] * wv;
            a2 += x[2][k] * wv; a3 += x[3][k] * wv;
        }
        xw[(long)(bs0 + 0) * G4 + g] = a0;
        xw[(long)(bs0 + 1) * G4 + g] = a1;
        xw[(long)(bs0 + 2) * G4 + g] = a2;
        xw[(long)(bs0 + 3) * G4 + g] = a3;
    }
}

// ---------------------------------------------------------------- LSTM: weights in registers
__global__ __launch_bounds__(512)
void lstm_kernel(const float* __restrict__ xw, const float* __restrict__ Whh,
                 float* __restrict__ qh_emb, float* __restrict__ qnode) {
    int b = blockIdx.x, tid = threadIdx.x;
    __shared__ __align__(16) float hs[TT];
    __shared__ float cs[TT];
    __shared__ float gs[G4];
    float4 w[25];
    if (tid < G4) {
        const float4* wr = (const float4*)(Whh + (long)tid * TT);
        #pragma unroll
        for (int j = 0; j < 25; ++j) w[j] = wr[j];
    }
    if (tid < TT) { hs[tid] = 0.f; cs[tid] = 0.f; }
    __syncthreads();
    for (int s = 0; s < LQ_; ++s) {
        if (tid < G4) {
            const float4* hv4 = (const float4*)hs;
            float a0 = 0.f, a1 = 0.f, a2 = 0.f, a3 = 0.f;
            #pragma unroll
            for (int j = 0; j < 25; ++j) {
                float4 hv = hv4[j];
                a0 += hv.x * w[j].x; a1 += hv.y * w[j].y;
                a2 += hv.z * w[j].z; a3 += hv.w * w[j].w;
            }
            gs[tid] = xw[((long)b * LQ_ + s) * G4 + tid] + (a0 + a1) + (a2 + a3);
        }
        __syncthreads();
        if (tid < TT) {
            float ci = sigm(gs[TT + tid]) * cs[tid] + sigm(gs[tid]) * tanhf(gs[2 * TT + tid]);
            float hi = sigm(gs[3 * TT + tid]) * tanhf(ci);
            cs[tid] = ci;
            hs[tid] = hi;
            qh_emb[((long)b * LQ_ + s) * TT + tid] = hi;
            if (s == LQ_ - 1) qnode[b * TT + tid] = hi;
        }
        __syncthreads();
    }
}

// ---------------------------------------------------------------- multi-output MFMA GEMM
// For w < nw: Y_w = act_w( X @ W_w.T + bias_w*bscale_w[r] + add_w[r,:] + cvec_w[r/EE,:] )
struct GOut {
    const float* W; int wstride;
    const float* bias;
    const float* bscale;
    const unsigned short* addb;   // bf16 add matrix (or null)
    const float* addf;            // f32 add matrix (or null)
    const float* cvec;            // per-batch row vector (or null)
    void* Y; int y_bf16; int relu;
};
struct GArgs {
    const void* X; int x_bf16;
    const int* gidx;
    long rows;
    int nw;
    GOut o[3];
};

__global__ __launch_bounds__(256)
void gemm_multi_kernel(GArgs a) {
    __shared__ __align__(16) short sX[64 * 136];    // 17408 B
    __shared__ __align__(16) short sW[112 * 136];   // 30464 B; aliased by sOut (26624 B)
    float* sOut = (float*)sW;
    int tid = threadIdx.x;
    long r0 = (long)blockIdx.x * 64;
    // ---- stage X (bf16 short4 or f32 float4 -> bf16)
    for (int i = tid; i < 64 * 25; i += 256) {
        int r = i / 25, c = i % 25;
        long rr = r0 + r;
        ushort4 v; v.x = 0; v.y = 0; v.z = 0; v.w = 0;
        if (rr < a.rows) {
            long xr = a.gidx ? (long)a.gidx[rr] : rr;
            if (a.x_bf16) {
                v = *(const ushort4*)((const unsigned short*)a.X + xr * TT + c * 4);
            } else {
                float4 f = *(const float4*)((const float*)a.X + xr * TT + c * 4);
                v.x = f2bf(f.x); v.y = f2bf(f.y); v.z = f2bf(f.z); v.w = f2bf(f.w);
            }
        }
        *(ushort4*)&sX[r * 136 + c * 4] = v;
    }
    for (int i = tid; i < 64 * 28; i += 256) {       // zero k-pad [100,128)
        int r = i / 28, k = TT + i % 28;
        sX[r * 136 + k] = 0;
    }
    int lane = tid & 63, wv = tid >> 6;
    int arow = lane & 15, agrp = lane >> 4;
    int t_lo = lane & 15, r_hi = (lane >> 4) * 4;
    #pragma unroll
    for (int w = 0; w < 3; ++w) {
        if (w >= a.nw) break;
        // ---- stage W_w (f32 -> bf16), zero-pad
        for (int i = tid; i < 112 * 32; i += 256) {
            int t = i / 32, k = (i % 32) * 4;
            ushort4 v; v.x = 0; v.y = 0; v.z = 0; v.w = 0;
            if (t < TT && k < TT) {
                float4 f = *(const float4*)(a.o[w].W + (long)t * a.o[w].wstride + k);
                v.x = f2bf(f.x); v.y = f2bf(f.y); v.z = f2bf(f.z); v.w = f2bf(f.w);
            }
            *(ushort4*)&sW[t * 136 + k] = v;
        }
        __syncthreads();
        // ---- MFMA
        f32x4 acc[7];
        #pragma unroll
        for (int n = 0; n < 7; ++n) acc[n] = (f32x4){0.f, 0.f, 0.f, 0.f};
        #pragma unroll
        for (int kk = 0; kk < 4; ++kk) {
            bf16x8 av = *(const bf16x8*)&sX[(wv * 16 + arow) * 136 + kk * 32 + agrp * 8];
            #pragma unroll
            for (int n = 0; n < 7; ++n) {
                bf16x8 bv = *(const bf16x8*)&sW[(n * 16 + arow) * 136 + kk * 32 + agrp * 8];
                acc[n] = __builtin_amdgcn_mfma_f32_16x16x32_bf16(av, bv, acc[n], 0, 0, 0);
            }
        }
        __syncthreads();   // all MFMA reads of sW done before sOut overwrite
        // ---- acc -> sOut (transpose to row-major)
        #pragma unroll
        for (int n = 0; n < 7; ++n) {
            int t = n * 16 + t_lo;
            if (t < TT) {
                #pragma unroll
                for (int j = 0; j < 4; ++j)
                    sOut[(wv * 16 + r_hi + j) * 104 + t] = acc[n][j];
            }
        }
        __syncthreads();
        // ---- coalesced epilogue + store
        for (int i = tid; i < 64 * 25; i += 256) {
            int r = i / 25, c = i % 25;
            long rr = r0 + r;
            if (rr < a.rows) {
                float4 v = *(float4*)&sOut[r * 104 + c * 4];
                if (a.o[w].bias) {
                    float bs = a.o[w].bscale ? a.o[w].bscale[rr] : 1.f;
                    float4 bv = *(const float4*)(a.o[w].bias + c * 4);
                    v.x += bv.x * bs; v.y += bv.y * bs; v.z += bv.z * bs; v.w += bv.w * bs;
                }
                if (a.o[w].addb) {
                    ushort4 ad = *(const ushort4*)(a.o[w].addb + rr * TT + c * 4);
                    v.x += bf2f(ad.x); v.y += bf2f(ad.y); v.z += bf2f(ad.z); v.w += bf2f(ad.w);
                }
                if (a.o[w].addf) {
                    float4 ad = *(const float4*)(a.o[w].addf + rr * TT + c * 4);
                    v.x += ad.x; v.y += ad.y; v.z += ad.z; v.w += ad.w;
                }
                if (a.o[w].cvec) {
                    float4 cv = *(const float4*)(a.o[w].cvec + (long)(rr / EE) * TT + c * 4);
                    v.x += cv.x; v.y += cv.y; v.z += cv.z; v.w += cv.w;
                }
                if (a.o[w].relu) {
                    v.x = fmaxf(v.x, 0.f); v.y = fmaxf(v.y, 0.f);
                    v.z = fmaxf(v.z, 0.f); v.w = fmaxf(v.w, 0.f);
                }
                if (a.o[w].y_bf16) {
                    ushort4 ov;
                    ov.x = f2bf(v.x); ov.y = f2bf(v.y); ov.z = f2bf(v.z); ov.w = f2bf(v.w);
                    *(ushort4*)((unsigned short*)a.o[w].Y + rr * TT + c * 4) = ov;
                } else {
                    *(float4*)((float*)a.o[w].Y + rr * TT + c * 4) = v;
                }
            }
        }
        __syncthreads();   // stores done before next W staging
    }
}

// ---------------------------------------------------------------- compose: C = A @ B, cb = A@ab + bb
__global__ __launch_bounds__(128)
void compose_kernel(const float* __restrict__ A, const float* __restrict__ B,
                    const float* __restrict__ ab, const float* __restrict__ bb,
                    float* __restrict__ C, float* __restrict__ cb) {
    int i = blockIdx.x, j = threadIdx.x;
    __shared__ float arow[TT];
    if (j < TT) arow[j] = A[i * TT + j];
    __syncthreads();
    if (j < TT) {
        float acc = 0.f;
        for (int k = 0; k < TT; ++k) acc += arow[k] * B[k * TT + j];
        C[i * TT + j] = acc;
    }
    if (j == 0) {
        float acc = bb[i];
        for (int k = 0; k < TT; ++k) acc += arow[k] * ab[k];
        cb[i] = acc;
    }
}

// ---------------------------------------------------------------- Wsc (fused sim/softmax/att)
__global__ __launch_bounds__(256)
void wsc_kernel(const float* __restrict__ qh_emb, const int* __restrict__ qtext,
                const unsigned short* __restrict__ ent_f, const int* __restrict__ rel,
                float* __restrict__ Wsc) {
    int b = blockIdx.x >> 4;
    int chunk = blockIdx.x & 15;
    __shared__ __align__(16) float qh[LQ_ * TT];
    __shared__ float msk[LQ_];
    for (int i = threadIdx.x; i < LQ_ * TT; i += 256) qh[i] = qh_emb[(long)b * LQ_ * TT + i];
    for (int i = threadIdx.x; i < LQ_; i += 256)
        msk[i] = (qtext[b * LQ_ + i] != 0) ? 0.f : VERY_NEG_;
    __syncthreads();
    int f = chunk * 256 + threadIdx.x;
    if (f >= FF) return;
    long bf = (long)b * FF + f;
    const unsigned short* fr = ent_f + (long)rel[bf] * TT;
    float sim[LQ_];
    #pragma unroll
    for (int l = 0; l < LQ_; ++l) sim[l] = 0.f;
    for (int kq = 0; kq < 25; ++kq) {
        ushort4 x4 = *(const ushort4*)(fr + kq * 4);
        float x0 = bf2f(x4.x), x1 = bf2f(x4.y), x2 = bf2f(x4.z), x3 = bf2f(x4.w);
        #pragma unroll
        for (int l = 0; l < LQ_; ++l) {
            float4 q = ((const float4*)(qh + l * TT))[kq];
            sim[l] += x0 * q.x + x1 * q.y + x2 * q.z + x3 * q.w;
        }
    }
    float mx = -INFINITY;
    #pragma unroll
    for (int l = 0; l < LQ_; ++l) {
        sim[l] *= 0.1f;  // /sqrt(100)
        mx = fmaxf(mx, sim[l] + msk[l]);
    }
    float ssum = 0.f, wsum = 0.f;
    #pragma unroll
    for (int l = 0; l < LQ_; ++l) {
        float p = expf(sim[l] + msk[l] - mx);
        ssum += p;
        wsum += p * sim[l];
    }
    Wsc[bf] = wsum / ssum;
}

// ---------------------------------------------------------------- row max over facts
__global__ __launch_bounds__(256)
void rowmax_kernel(const float* __restrict__ Wsc, float* __restrict__ bmax) {
    int b = blockIdx.x, tid = threadIdx.x;
    __shared__ float red[256];
    float m = -INFINITY;
    for (int f = tid; f < FF; f += 256) m = fmaxf(m, Wsc[(long)b * FF + f]);
    red[tid] = m;
    __syncthreads();
    for (int s = 128; s; s >>= 1) {
        if (tid < s) red[tid] = fmaxf(red[tid], red[tid + s]);
        __syncthreads();
    }
    if (tid == 0) bmax[b] = red[0];
}

// ---------------------------------------------------------------- W_tilde + e2f_softmax scatter + tail counts
__global__ __launch_bounds__(256)
void wtilde_kernel(const float* __restrict__ Wsc, const float* __restrict__ bmax,
                   const int* __restrict__ head, const int* __restrict__ tail,
                   float* __restrict__ W_tilde, float* __restrict__ e2f_sm,
                   float* __restrict__ cnt) {
    int idx = blockIdx.x * 256 + threadIdx.x;
    if (idx >= BB * FF) return;
    int b = idx / FF;
    float wt = expf(Wsc[idx] - bmax[b]);
    W_tilde[idx] = wt;
    atomicAdd(&e2f_sm[(long)b * EE + head[idx]], wt);
    atomicAdd(&cnt[(long)b * EE + tail[idx]], 1.f);
}

// ---------------------------------------------------------------- per-layer tiny: q2e_vec + cvecs
__global__ __launch_bounds__(128)
void qvec_kernel(const float* __restrict__ qnode,
                 const float* __restrict__ q2eW, const float* __restrict__ q2eb,
                 const float* __restrict__ e2eW, const float* __restrict__ e2eb,
                 const float* __restrict__ e2qW, const float* __restrict__ e2qb,
                 float* __restrict__ q2e_vec, float* __restrict__ cvec_e2e,
                 float* __restrict__ cvec_e2q) {
    int b = blockIdx.x, t = threadIdx.x;
    __shared__ float qn[TT], qv[TT];
    if (t < TT) qn[t] = qnode[b * TT + t];
    __syncthreads();
    if (t < TT) {
        float acc = q2eb[t];
        for (int k = 0; k < TT; ++k) acc += qn[k] * q2eW[t * TT + k];
        qv[t] = acc;
        q2e_vec[b * TT + t] = acc;
    }
    __syncthreads();
    if (t < TT) {
        float a1 = e2eb[t], a2 = e2qb[t];
        for (int k = 0; k < TT; ++k) {
            a1 += qv[k] * e2eW[(long)t * 300 + TT + k];
            a2 += qv[k] * e2qW[(long)t * 300 + TT + k];
        }
        cvec_e2e[b * TT + t] = a1;
        cvec_e2q[b * TT + t] = a2;
    }
}

// ---------------------------------------------------------------- per-fact norm + pagerank scatter
__global__ __launch_bounds__(256)
void norm_kernel(const float* __restrict__ W_tilde, const float* __restrict__ pr,
                 const float* __restrict__ e2f_sm, const int* __restrict__ head,
                 const int* __restrict__ tail, float* __restrict__ norm,
                 float* __restrict__ pr_acc) {
    int idx = blockIdx.x * 256 + threadIdx.x;
    if (idx >= BB * FF) return;
    int b = idx / FF;
    int h = head[idx];
    float n = W_tilde[idx] * pr[(long)b * EE + h] / fmaxf(e2f_sm[(long)b * EE + h], EPS_);
    norm[idx] = n;
    if (n != 0.f) atomicAdd(&pr_acc[(long)b * EE + tail[idx]], n);
}

// ---------------------------------------------------------------- e2f elementwise scatter (bf16 in)
__global__ __launch_bounds__(256)
void e2f_elem_kernel(const unsigned short* __restrict__ ent_kbs,
                     const unsigned short* __restrict__ kbh,
                     const float* __restrict__ norm, const int* __restrict__ rel,
                     const int* __restrict__ head, const int* __restrict__ tail,
                     float* __restrict__ eacc) {
    long idx = (long)blockIdx.x * 256 + threadIdx.x;
    if (idx >= (long)BB * FF * 25) return;
    int q = (int)(idx % 25);
    long bf = idx / 25;
    int b = (int)(bf / FF);
    float n = norm[bf];
    if (n == 0.f) return;
    ushort4 s4 = *(const ushort4*)(ent_kbs + (long)rel[bf] * TT + q * 4);
    ushort4 k4 = *(const ushort4*)(kbh + ((long)b * EE + head[bf]) * TT + q * 4);
    float* dst = eacc + ((long)b * EE + tail[bf]) * TT + q * 4;
    atomicAdd(dst + 0, fmaxf(bf2f(s4.x) + bf2f(k4.x), 0.f) * n);
    atomicAdd(dst + 1, fmaxf(bf2f(s4.y) + bf2f(k4.y), 0.f) * n);
    atomicAdd(dst + 2, fmaxf(bf2f(s4.z) + bf2f(k4.z), 0.f) * n);
    atomicAdd(dst + 3, fmaxf(bf2f(s4.w) + bf2f(k4.w), 0.f) * n);
}

// ---------------------------------------------------------------- pagerank update
__global__ void pr_update_kernel(const float* __restrict__ pr_acc, float* __restrict__ pr,
                                 float* __restrict__ out2) {
    int i = blockIdx.x * 256 + threadIdx.x;
    if (i < BB * EE) {
        float v = 0.8f * pr_acc[i] + 0.2f * pr[i];
        pr[i] = v;
        if (out2) out2[i] = v;
    }
}

// ---------------------------------------------------------------- weighted reductions s1,s3,prsum
#define RCH 50
__global__ __launch_bounds__(128)
void reduce_kernel(const float* __restrict__ pr, const unsigned short* __restrict__ ent,
                   const int* __restrict__ gidx, const unsigned short* __restrict__ f2e,
                   float* __restrict__ s1, float* __restrict__ s3, float* __restrict__ prsum) {
    int b = blockIdx.x / (EE / RCH), ch = blockIdx.x % (EE / RCH);
    int e0 = ch * RCH, tid = threadIdx.x;
    __shared__ float prl[RCH];
    __shared__ long erow[RCH];
    if (tid < RCH) {
        long idx = (long)b * EE + e0 + tid;
        prl[tid] = pr[idx];
        erow[tid] = gidx ? (long)gidx[idx] : idx;
    }
    __syncthreads();
    if (tid == 0) {
        float s = 0.f;
        for (int e = 0; e < RCH; ++e) s += prl[e];
        if (s != 0.f) atomicAdd(&prsum[b], s);
    }
    if (tid < TT) {
        float a1 = 0.f, a3 = 0.f;
        for (int e = 0; e < RCH; ++e) {
            float p = prl[e];
            if (p != 0.f) {
                a1 += p * bf2f(ent[erow[e] * TT + tid]);
                a3 += p * bf2f(f2e[((long)b * EE + e0 + e) * TT + tid]);
            }
        }
        atomicAdd(&s1[b * TT + tid], a1);
        atomicAdd(&s3[b * TT + tid], a3);
    }
}

// ---------------------------------------------------------------- qnode update
__global__ __launch_bounds__(128)
void qnode_kernel(const float* __restrict__ s1, const float* __restrict__ s3,
                  const float* __restrict__ prsum, const float* __restrict__ cvec_e2q,
                  const float* __restrict__ e2qW, float* __restrict__ qnode,
                  float* __restrict__ out2) {
    int b = blockIdx.x, t = threadIdx.x;
    __shared__ float s1l[TT], s3l[TT];
    if (t < TT) { s1l[t] = s1[b * TT + t]; s3l[t] = s3[b * TT + t]; }
    __syncthreads();
    if (t < TT) {
        float acc = prsum[b] * cvec_e2q[b * TT + t];
        const float* wr = e2qW + (long)t * 300;
        for (int k = 0; k < TT; ++k) acc += s1l[k] * wr[k] + s3l[k] * wr[200 + k];
        qnode[b * TT + t] = acc;
        if (out2) out2[b * TT + t] = acc;
    }
}

// ================================================================ host
extern "C" void kernel_launch(void* const* d_in, const int* in_sizes, int n_in,
                              void* d_out, int out_size, void* d_ws, size_t ws_size,
                              hipStream_t stream) {
    const float* word_emb   = (const float*)d_in[0];
    const float* entity_emb = (const float*)d_in[1];
    const float* ent_W      = (const float*)d_in[2];
    const float* ent_b      = (const float*)d_in[3];
    const float* lstm_Wih   = (const float*)d_in[4];
    const float* lstm_Whh   = (const float*)d_in[5];
    const float* lstm_bih   = (const float*)d_in[6];
    const float* lstm_bhh   = (const float*)d_in[7];
    const float* q2e_W      = (const float*)d_in[8];
    const float* q2e_b      = (const float*)d_in[9];
    const float* e2q_W      = (const float*)d_in[10];
    const float* e2q_b      = (const float*)d_in[11];
    const float* e2e_W      = (const float*)d_in[12];
    const float* e2e_b      = (const float*)d_in[13];
    const float* kbh_W      = (const float*)d_in[14];
    const float* kbh_b      = (const float*)d_in[15];
    const float* kbt_W      = (const float*)d_in[16];
    const float* kbt_b      = (const float*)d_in[17];
    const float* kbs_W      = (const float*)d_in[18];
    const float* kbs_b      = (const float*)d_in[19];
    const float* q2e_adj    = (const float*)d_in[20];
    const int* query_text   = (const int*)d_in[21];
    const int* local_entity = (const int*)d_in[22];
    const int* kb_fact_rel  = (const int*)d_in[23];
    const int* head_idx     = (const int*)d_in[24];
    const int* tail_idx     = (const int*)d_in[25];
    float* out = (float*)d_out;

    char* base = (char*)d_ws;
    size_t off = 0;
    auto alloc = [&](size_t bytes) {
        void* p = base + off;
        off = (off + bytes + 255) & ~(size_t)255;
        return p;
    };
    const size_t NE = (size_t)BB * EE;          // 64000
    unsigned short* emb_bf  = (unsigned short*)alloc((size_t)EV_ * TT * 2);
    unsigned short* ent_f   = (unsigned short*)alloc((size_t)EV_ * TT * 2);
    unsigned short* kbs0    = (unsigned short*)alloc((size_t)EV_ * TT * 2);
    unsigned short* kbs1    = (unsigned short*)alloc((size_t)EV_ * TT * 2);
    unsigned short* entB    = (unsigned short*)alloc(NE * TT * 2);
    unsigned short* kbh_bf  = (unsigned short*)alloc(NE * TT * 2);   // aliased as f2e
    unsigned short* kbs_e   = (unsigned short*)alloc(NE * TT * 2);
    float* tmp              = (float*)alloc(NE * TT * 4);
    float* eacc             = (float*)alloc(NE * TT * 4);            // contiguous with pr_acc
    float* pr_acc           = (float*)alloc(NE * 4);
    float* xw               = (float*)alloc((size_t)BB * LQ_ * G4 * 4);
    float* qh_emb           = (float*)alloc((size_t)BB * LQ_ * TT * 4);
    float* WihT             = (float*)alloc((size_t)G4 * EMB_ * 4);
    float* Wsc              = (float*)alloc((size_t)BB * FF * 4);
    float* W_tilde          = (float*)alloc((size_t)BB * FF * 4);
    float* normf            = (float*)alloc((size_t)BB * FF * 4);
    float* bmaxb            = (float*)alloc(BB * 4);
    float* e2f_sm           = (float*)alloc(NE * 4);                 // contiguous with cnt
    float* cnt              = (float*)alloc(NE * 4);
    float* pr               = (float*)alloc(NE * 4);
    float* qnode            = (float*)alloc((size_t)BB * TT * 4);
    float* q2e_vec          = (float*)alloc((size_t)BB * TT * 4);
    float* cvec_e2e         = (float*)alloc((size_t)BB * TT * 4);
    float* cvec_e2q         = (float*)alloc((size_t)BB * TT * 4);
    float* s1               = (float*)alloc((size_t)BB * TT * 4);    // s1,s3,prsum contiguous
    float* s3               = (float*)alloc((size_t)BB * TT * 4);
    float* prsum            = (float*)alloc(BB * 4);
    float* Ckbs0            = (float*)alloc((size_t)TT * TT * 4);
    float* Ckbs1            = (float*)alloc((size_t)TT * TT * 4);
    float* cb0              = (float*)alloc(TT * 4);
    float* cb1              = (float*)alloc(TT * 4);
    unsigned short* f2e = kbh_bf;  // alias: kbh dead after e2f_elem

    // ---- LSTM path
    transpose_kernel<<<(G4 * EMB_ + 255) / 256, 256, 0, stream>>>(lstm_Wih, WihT, G4, EMB_);
    xw_kernel<<<BB * LQ_ / 4, 256, 0, stream>>>(word_emb, query_text, WihT, lstm_bih, lstm_bhh, xw);
    lstm_kernel<<<BB, 512, 0, stream>>>(xw, lstm_Whh, qh_emb, qnode);

    // ---- composed vocab tables: ent_f, kbs0, kbs1 in ONE pass over bf16 entity_emb
    cvt_bf16_kernel<<<(EV_ * TT / 4 + 255) / 256, 256, 0, stream>>>(entity_emb, emb_bf,
                                                                    (long)EV_ * TT / 4);
    compose_kernel<<<TT, 128, 0, stream>>>(kbs_W, ent_W, ent_b, kbs_b, Ckbs0, cb0);
    compose_kernel<<<TT, 128, 0, stream>>>(kbs_W + TT * TT, ent_W, ent_b, kbs_b + TT,
                                           Ckbs1, cb1);
    {
        GArgs g{};
        g.X = emb_bf; g.x_bf16 = 1; g.gidx = nullptr; g.rows = EV_; g.nw = 3;
        g.o[0].W = ent_W; g.o[0].wstride = TT; g.o[0].bias = ent_b;
        g.o[0].Y = ent_f; g.o[0].y_bf16 = 1;
        g.o[1].W = Ckbs0; g.o[1].wstride = TT; g.o[1].bias = cb0;
        g.o[1].Y = kbs0; g.o[1].y_bf16 = 1;
        g.o[2].W = Ckbs1; g.o[2].wstride = TT; g.o[2].bias = cb1;
        g.o[2].Y = kbs1; g.o[2].y_bf16 = 1;
        gemm_multi_kernel<<<(EV_ + 63) / 64, 256, 0, stream>>>(g);
    }

    // ---- attention scores -> W_tilde, e2f_softmax, counts
    wsc_kernel<<<BB * 16, 256, 0, stream>>>(qh_emb, query_text, ent_f, kb_fact_rel, Wsc);
    rowmax_kernel<<<BB, 256, 0, stream>>>(Wsc, bmaxb);
    hipMemsetAsync(e2f_sm, 0, 2 * NE * 4, stream);
    wtilde_kernel<<<(BB * FF + 255) / 256, 256, 0, stream>>>(Wsc, bmaxb, head_idx, tail_idx,
                                                             W_tilde, e2f_sm, cnt);
    hipMemcpyAsync(pr, q2e_adj, NE * 4, hipMemcpyDeviceToDevice, stream);

    // ---- GNN layers
    for (int i = 0; i < 2; ++i) {
        const unsigned short* kbs_tab = i ? kbs1 : kbs0;
        qvec_kernel<<<BB, 128, 0, stream>>>(qnode, q2e_W + i * TT * TT, q2e_b + i * TT,
                                            e2e_W + i * TT * 300, e2e_b + i * TT,
                                            e2q_W + i * TT * 300, e2q_b + i * TT,
                                            q2e_vec, cvec_e2e, cvec_e2q);
        // one pass over ent_in: kbh, kbs_e, e2e-part1(tmp)
        {
            GArgs g{};
            g.X = i ? (const void*)entB : (const void*)ent_f;
            g.x_bf16 = 1;
            g.gidx = i ? nullptr : local_entity;
            g.rows = (long)NE; g.nw = 3;
            g.o[0].W = kbh_W + i * TT * TT; g.o[0].wstride = TT; g.o[0].bias = kbh_b + i * TT;
            g.o[0].Y = kbh_bf; g.o[0].y_bf16 = 1;
            g.o[1].W = kbs_W + i * TT * TT; g.o[1].wstride = TT; g.o[1].bias = kbs_b + i * TT;
            g.o[1].Y = kbs_e; g.o[1].y_bf16 = 1;
            g.o[2].W = e2e_W + i * TT * 300; g.o[2].wstride = 300;
            g.o[2].Y = tmp; g.o[2].y_bf16 = 0;
            gemm_multi_kernel<<<(int)(NE / 64), 256, 0, stream>>>(g);
        }
        hipMemsetAsync(eacc, 0, NE * TT * 4 + NE * 4, stream);  // eacc + pr_acc
        norm_kernel<<<(BB * FF + 255) / 256, 256, 0, stream>>>(W_tilde, pr, e2f_sm, head_idx,
                                                               tail_idx, normf, pr_acc);
        e2f_elem_kernel<<<(int)(((long)BB * FF * 25 + 255) / 256), 256, 0, stream>>>(
            kbs_tab, kbh_bf, normf, kb_fact_rel, head_idx, tail_idx, eacc);
        // f2e = relu(kbs_e + eacc@kbt.T + kbt_b*cnt)   (f2e aliases kbh_bf)
        {
            GArgs g{};
            g.X = eacc; g.x_bf16 = 0; g.gidx = nullptr; g.rows = (long)NE; g.nw = 1;
            g.o[0].W = kbt_W + i * TT * TT; g.o[0].wstride = TT;
            g.o[0].bias = kbt_b + i * TT; g.o[0].bscale = cnt;
            g.o[0].addb = kbs_e;
            g.o[0].Y = (void*)f2e; g.o[0].y_bf16 = 1; g.o[0].relu = 1;
            gemm_multi_kernel<<<(int)(NE / 64), 256, 0, stream>>>(g);
        }
        pr_update_kernel<<<(int)((NE + 255) / 256), 256, 0, stream>>>(
            pr_acc, pr, (i == 1) ? out + 6406400 : nullptr);
        hipMemsetAsync(s1, 0, (size_t)(2 * BB * TT + BB) * 4, stream);
        reduce_kernel<<<BB * (EE / RCH), 128, 0, stream>>>(
            pr, i ? entB : ent_f, i ? nullptr : local_entity, f2e, s1, s3, prsum);
        qnode_kernel<<<BB, 128, 0, stream>>>(s1, s3, prsum, cvec_e2q, e2q_W + i * TT * 300,
                                             qnode, (i == 1) ? out + 6400000 : nullptr);
        // ent_out = relu(tmp + f2e@W3.T + cvec_e2e)
        {
            GArgs g{};
            g.X = f2e; g.x_bf16 = 1; g.gidx = nullptr; g.rows = (long)NE; g.nw = 1;
            g.o[0].W = e2e_W + i * TT * 300 + 200; g.o[0].wstride = 300;
            g.o[0].addf = tmp; g.o[0].cvec = cvec_e2e; g.o[0].relu = 1;
            g.o[0].Y = i ? (void*)out : (void*)entB; g.o[0].y_bf16 = i ? 0 : 1;
            gemm_multi_kernel<<<(int)(NE / 64), 256, 0, stream>>>(g);
        }
    }
}